// Round 13
// baseline (268.537 us; speedup 1.0000x reference)
//
#include <hip/hip_runtime.h>
#include <hip/hip_bf16.h>

typedef __hip_bfloat16 bf16;
typedef __attribute__((ext_vector_type(8))) __bf16 bf16x8;
typedef __attribute__((ext_vector_type(4))) float f32x4;

// ---------------- problem constants ----------------
constexpr int BSZ = 4, SEQ = 4096, DMODEL = 512;
constexpr int DSTATE = 128, HEADDIM = 64, DINNER = 1024, NHEADS = 16, CHUNK = 128;
constexpr int CONVDIM = DINNER + 2 * DSTATE;              // 1280
constexpr int DINPROJ = 2 * DINNER + 2 * DSTATE + NHEADS; // 2320
constexpr int NPAD = 2432;                                // 19*128, padded N for in_proj
constexpr int MTOT = BSZ * SEQ;                           // 16384
constexpr int NCHUNK = SEQ / CHUNK;                       // 32

// ---------------- workspace layout (bytes) ----------------
constexpr size_t OFF_Z    = 0;                                               // bf16 [MTOT][DINNER]
constexpr size_t OFF_XBC  = OFF_Z    + (size_t)MTOT * DINNER * 2;            // bf16 [MTOT][CONVDIM]
constexpr size_t OFF_DT   = OFF_XBC  + (size_t)MTOT * CONVDIM * 2;           // f32  [MTOT][NHEADS]
constexpr size_t OFF_XS   = OFF_DT   + (size_t)MTOT * NHEADS * 4;            // bf16 [MTOT][DINNER]
constexpr size_t OFF_B    = OFF_XS   + (size_t)MTOT * DINNER * 2;            // bf16 [MTOT][DSTATE]
constexpr size_t OFF_C    = OFF_B    + (size_t)MTOT * DSTATE * 2;            // bf16 [MTOT][DSTATE]
constexpr size_t OFF_G    = OFF_C    + (size_t)MTOT * DSTATE * 2;            // bf16 [B*NC][128][128]
constexpr size_t OFF_ASUM = OFF_G    + (size_t)BSZ * NCHUNK * CHUNK * CHUNK * 2; // f32
constexpr size_t WS_NEED  = OFF_ASUM + 8192;                                 // ~117MiB

static __device__ __forceinline__ float sigmoidf_(float x) { return 1.f / (1.f + __expf(-x)); }
static __device__ __forceinline__ unsigned short f2bf_bits(float f) {
    __hip_bfloat16 h = __float2bfloat16(f);
    return *reinterpret_cast<unsigned short*>(&h);
}
static __device__ __forceinline__ float bfbits2f(unsigned short u) {
    return __bfloat162float(*reinterpret_cast<bf16*>(&u));
}
struct us4 { unsigned short a, b, c, d; };
static __device__ __forceinline__ us4 pack4(const f32x4 v) {
    return { f2bf_bits(v[0]), f2bf_bits(v[1]), f2bf_bits(v[2]), f2bf_bits(v[3]) };
}

__global__ void k_sentinel(float* out) { out[0] = 1.0e9f; }

// ================= cast kernels =================
// merged front cast: x -> bf16 AND W_in -> bf16 (padded) in one launch
constexpr int NX4 = MTOT * DMODEL / 4;
constexpr int NW4 = NPAD * (DMODEL / 4);
__global__ __launch_bounds__(256) void k_cast_front(
    const float* __restrict__ x, const float* __restrict__ W,
    bf16* __restrict__ xb, bf16* __restrict__ Wb)
{
    int i = blockIdx.x * 256 + threadIdx.x;
    if (i < NX4) {
        float4 f = ((const float4*)x)[i];
        us4 v = { f2bf_bits(f.x), f2bf_bits(f.y), f2bf_bits(f.z), f2bf_bits(f.w) };
        ((us4*)xb)[i] = v;
    } else {
        int j = i - NX4;
        if (j >= NW4) return;
        int row = j / (DMODEL / 4);
        us4 v;
        if (row < DINPROJ) {
            float4 f = ((const float4*)W)[j];
            v = { f2bf_bits(f.x), f2bf_bits(f.y), f2bf_bits(f.z), f2bf_bits(f.w) };
        } else {
            v = { 0, 0, 0, 0 };
        }
        ((us4*)Wb)[j] = v;
    }
}

__global__ __launch_bounds__(256) void k_cast_x(const float* __restrict__ in, bf16* __restrict__ out, int n4) {
    int i = blockIdx.x * 256 + threadIdx.x;
    if (i >= n4) return;
    float4 f = ((const float4*)in)[i];
    us4 v = { f2bf_bits(f.x), f2bf_bits(f.y), f2bf_bits(f.z), f2bf_bits(f.w) };
    ((us4*)out)[i] = v;
}

// ================= MFMA GEMM core: R5/R10 proven config (85us measured, best of 5 variants) =================
// 3-buf BK=32, BOTH A and B staged via inverse-swizzled global_load_lds, vmcnt(4).
// 128x128 tile, 4 waves (2x2). LDS per buffer: 64 rows x 128B holding 128 tile rows
// as 2 half-rows; logical chunk L = phys ^ (row&7); tile row = (L>>2)*64 + row.
typedef const __attribute__((address_space(1))) void* gas_t;
typedef __attribute__((address_space(3))) void* las_t;
static __device__ __forceinline__ void gload_lds16(const void* g, void* l) {
    __builtin_amdgcn_global_load_lds((gas_t)g, (las_t)l, 16, 0, 0);
}

template<int K>
static __device__ __forceinline__ void gemm_core(
    const bf16* __restrict__ A, const bf16* __restrict__ B,
    int m0, int n0, bf16* ldsA, bf16* ldsB, f32x4 acc[4][4])
{
    constexpr int NT = K / 32;
    const int tid = threadIdx.x;
    const int l = tid & 63, w = tid >> 6;
    const int wr = w >> 1, wc = w & 1;
    const int lq = l & 15, lk = l >> 4;

    auto stage = [&](int buf, int t) {
        const int k0 = t * 32;
        #pragma unroll
        for (int i = 0; i < 2; ++i) {
            int q = w * 16 + i * 8 + (l >> 3);   // LDS row [0,64)
            int p = l & 7;                        // phys 16B chunk
            int L = p ^ (q & 7);                  // logical chunk
            int ra = (L >> 2) * 64 + q;           // tile row [0,128)
            int ck = L & 3;                       // k-chunk (8 bf16)
            gload_lds16(A + (size_t)(m0 + ra) * K + k0 + ck * 8,
                        ldsA + buf * 4096 + (w * 16 + i * 8) * 64);
            gload_lds16(B + (size_t)(n0 + ra) * K + k0 + ck * 8,
                        ldsB + buf * 4096 + (w * 16 + i * 8) * 64);
        }
    };

    stage(0, 0);
    stage(1, 1);
    for (int t = 0; t < NT; ++t) {
        if (t + 1 < NT) asm volatile("s_waitcnt vmcnt(4)" ::: "memory");
        else            asm volatile("s_waitcnt vmcnt(0)" ::: "memory");
        __builtin_amdgcn_s_barrier();
        __builtin_amdgcn_sched_barrier(0);
        if (t + 2 < NT) stage((t + 2) % 3, t + 2);
        const int buf = t % 3;
        bf16x8 av[4], bv[4];
        #pragma unroll
        for (int f = 0; f < 4; ++f) {
            int ra = wr * 64 + f * 16 + lq;
            int qa = ra & 63, La = (ra >> 6) * 4 + lk, pa = La ^ (qa & 7);
            av[f] = *(const bf16x8*)(ldsA + buf * 4096 + qa * 64 + pa * 8);
            int rb = wc * 64 + f * 16 + lq;
            int qb = rb & 63, Lb = (rb >> 6) * 4 + lk, pb = Lb ^ (qb & 7);
            bv[f] = *(const bf16x8*)(ldsB + buf * 4096 + qb * 64 + pb * 8);
        }
        // swapped operands: D rows = n (B rows), cols = m -> acc[nf][mf]
        #pragma unroll
        for (int nf = 0; nf < 4; ++nf)
            #pragma unroll
            for (int mf = 0; mf < 4; ++mf)
                acc[nf][mf] = __builtin_amdgcn_mfma_f32_16x16x32_bf16(bv[nf], av[mf], acc[nf][mf], 0, 0, 0);
    }
}

static __device__ __forceinline__ void swz_block(int& bx, int& by) {
    int gx = gridDim.x;
    int nwg = gx * gridDim.y;
    int wg = by * gx + bx;
    int q = nwg >> 3;                    // nwg % 8 == 0 in all uses (bijective)
    wg = (wg & 7) * q + (wg >> 3);
    bx = wg % gx; by = wg / gx;
}

// ================= kernel 1: in_proj MFMA GEMM + split + softplus(dt) =================
__global__ __launch_bounds__(256) void k_gemm_in(
    const bf16* __restrict__ xb, const bf16* __restrict__ Wb,
    const float* __restrict__ dt_bias,
    bf16* __restrict__ z, bf16* __restrict__ xbc, float* __restrict__ dtb)
{
    __shared__ bf16 ldsA[3 * 4096];
    __shared__ bf16 ldsB[3 * 4096];
    int bx = blockIdx.x, by = blockIdx.y;
    swz_block(bx, by);
    const int m0 = by * 128, n0 = bx * 128;
    f32x4 acc[4][4] = {};
    gemm_core<DMODEL>(xb, Wb, m0, n0, ldsA, ldsB, acc);
    const int l = threadIdx.x & 63, w = threadIdx.x >> 6;
    const int wr = w >> 1, wc = w & 1, lq = l & 15, lk = l >> 4;
    const int mg = m0 + wr * 64, ng = n0 + wc * 64;
    if (n0 < DINNER) {                       // whole tile in z
        #pragma unroll
        for (int nf = 0; nf < 4; ++nf)
            #pragma unroll
            for (int mf = 0; mf < 4; ++mf) {
                int n = ng + nf * 16 + lk * 4;
                int m = mg + mf * 16 + lq;
                *(us4*)(z + (size_t)m * DINNER + n) = pack4(acc[nf][mf]);
            }
    } else if (n0 < DINNER + CONVDIM) {      // whole tile in xbc
        #pragma unroll
        for (int nf = 0; nf < 4; ++nf)
            #pragma unroll
            for (int mf = 0; mf < 4; ++mf) {
                int n = ng + nf * 16 + lk * 4 - DINNER;
                int m = mg + mf * 16 + lq;
                *(us4*)(xbc + (size_t)m * CONVDIM + n) = pack4(acc[nf][mf]);
            }
    } else {                                 // dt block (+ zero pad)
        #pragma unroll
        for (int nf = 0; nf < 4; ++nf)
            #pragma unroll
            for (int mf = 0; mf < 4; ++mf)
                #pragma unroll
                for (int j = 0; j < 4; ++j) {
                    int n = ng + nf * 16 + lk * 4 + j;
                    int m = mg + mf * 16 + lq;
                    if (n < DINPROJ) {
                        int h = n - (DINNER + CONVDIM);
                        float t = acc[nf][mf][j] + dt_bias[h];
                        dtb[(size_t)m * NHEADS + h] = (t > 20.f) ? t : log1pf(__expf(t));
                    }
                }
    }
}

// ================= kernel 8: out_proj MFMA GEMM + residual =================
__global__ __launch_bounds__(256) void k_gemm_out(
    const bf16* __restrict__ gb, const bf16* __restrict__ Wb,
    const float* __restrict__ xres, float* __restrict__ outp)
{
    __shared__ bf16 ldsA[3 * 4096];
    __shared__ bf16 ldsB[3 * 4096];
    int bx = blockIdx.x, by = blockIdx.y;
    swz_block(bx, by);
    const int m0 = by * 128, n0 = bx * 128;
    f32x4 acc[4][4] = {};
    gemm_core<DINNER>(gb, Wb, m0, n0, ldsA, ldsB, acc);
    const int l = threadIdx.x & 63, w = threadIdx.x >> 6;
    const int wr = w >> 1, wc = w & 1, lq = l & 15, lk = l >> 4;
    const int mg = m0 + wr * 64, ng = n0 + wc * 64;
    #pragma unroll
    for (int nf = 0; nf < 4; ++nf)
        #pragma unroll
        for (int mf = 0; mf < 4; ++mf) {
            int n = ng + nf * 16 + lk * 4;
            int m = mg + mf * 16 + lq;
            float4 r = *(const float4*)(xres + (size_t)m * DMODEL + n);
            float4 o = { r.x + acc[nf][mf][0], r.y + acc[nf][mf][1],
                         r.z + acc[nf][mf][2], r.w + acc[nf][mf][3] };
            *(float4*)(outp + (size_t)m * DMODEL + n) = o;
        }
}

// ================= kernel 2: causal depthwise conv(K=4) + SiLU + split =================
constexpr int CTOK = 16;
__global__ __launch_bounds__(320) void k_conv(
    const bf16* __restrict__ xbc, const float* __restrict__ cw, const float* __restrict__ cb,
    bf16* __restrict__ xs, bf16* __restrict__ Bm, bf16* __restrict__ Cm)
{
    const int m0 = blockIdx.x * CTOK;     // never crosses batch boundary (4096 % 16 == 0)
    const int c4 = threadIdx.x;           // [0,320)
    const int c = c4 * 4;
    const int l0 = m0 & 4095;
    float4 cbv = ((const float4*)cb)[c4];
    const float4 w0 = ((const float4*)cw)[c + 0];
    const float4 w1 = ((const float4*)cw)[c + 1];
    const float4 w2 = ((const float4*)cw)[c + 2];
    const float4 w3 = ((const float4*)cw)[c + 3];
    us4 rows[CTOK + 3];
    #pragma unroll
    for (int t = -3; t < CTOK; ++t) {
        int ll = l0 + t;
        if (ll >= 0) rows[t + 3] = *(const us4*)(xbc + (size_t)(m0 + t) * CONVDIM + c);
        else         rows[t + 3] = { 0, 0, 0, 0 };
    }
    #pragma unroll
    for (int t = 0; t < CTOK; ++t) {
        float a0 = cbv.x, a1 = cbv.y, a2 = cbv.z, a3 = cbv.w;
        #pragma unroll
        for (int k = 0; k < 4; ++k) {
            us4 v = rows[t + k];
            a0 += bfbits2f(v.a) * ((const float*)&w0)[k];
            a1 += bfbits2f(v.b) * ((const float*)&w1)[k];
            a2 += bfbits2f(v.c) * ((const float*)&w2)[k];
            a3 += bfbits2f(v.d) * ((const float*)&w3)[k];
        }
        us4 o = { f2bf_bits(a0 * sigmoidf_(a0)), f2bf_bits(a1 * sigmoidf_(a1)),
                  f2bf_bits(a2 * sigmoidf_(a2)), f2bf_bits(a3 * sigmoidf_(a3)) };
        int m = m0 + t;
        if (c < DINNER)               *(us4*)(xs + (size_t)m * DINNER + c) = o;
        else if (c < DINNER + DSTATE) *(us4*)(Bm + (size_t)m * DSTATE + (c - DINNER)) = o;
        else                          *(us4*)(Cm + (size_t)m * DSTATE + (c - DINNER - DSTATE)) = o;
    }
}

// ================= kernel 3: MFMA G = C · B^T per (b,chunk), vectorized stores =================
__global__ __launch_bounds__(64) void k_gmat(
    const bf16* __restrict__ Cm, const bf16* __restrict__ Bm, bf16* __restrict__ G)
{
    const int bc = blockIdx.z;
    const int q0 = blockIdx.x * 64, s0 = blockIdx.y * 64;
    const int row0 = bc * CHUNK;
    const int l = threadIdx.x;
    const int lq = l & 15, lk = l >> 4;
    f32x4 acc[4][4] = {};   // [fs][fq]
    #pragma unroll
    for (int kc = 0; kc < 4; ++kc) {
        bf16x8 av[4], bv[4];
        #pragma unroll
        for (int f = 0; f < 4; ++f) {
            av[f] = *(const bf16x8*)(Cm + (size_t)(row0 + q0 + f * 16 + lq) * DSTATE + kc * 32 + lk * 8);
            bv[f] = *(const bf16x8*)(Bm + (size_t)(row0 + s0 + f * 16 + lq) * DSTATE + kc * 32 + lk * 8);
        }
        #pragma unroll
        for (int fs = 0; fs < 4; ++fs)
            #pragma unroll
            for (int fq = 0; fq < 4; ++fq)
                acc[fs][fq] = __builtin_amdgcn_mfma_f32_16x16x32_bf16(bv[fs], av[fq], acc[fs][fq], 0, 0, 0);
    }
    #pragma unroll
    for (int fs = 0; fs < 4; ++fs)
        #pragma unroll
        for (int fq = 0; fq < 4; ++fq) {
            int q = q0 + fq * 16 + lq;
            int s = s0 + fs * 16 + lk * 4;
            *(us4*)(G + ((size_t)bc * CHUNK + q) * CHUNK + s) = pack4(acc[fs][fq]);
        }
}

// ================= kernel 4: MFMA SSD per (b,c,h): y = (L∘G)·X + D*xs ; states =================
__global__ __launch_bounds__(256) void k_ssd(
    const bf16* __restrict__ xs /* == y */, const bf16* __restrict__ Bm,
    const float* __restrict__ dtb, const float* __restrict__ A_log,
    const float* __restrict__ Dp, const bf16* __restrict__ G,
    bf16* __restrict__ y, bf16* __restrict__ states, float* __restrict__ asum)
{
    const int h = blockIdx.x, c = blockIdx.y, b = blockIdx.z;
    const int tid = threadIdx.x;
    const int l = tid & 63, w = tid >> 6;
    const int lq = l & 15, lk = l >> 4;
    __shared__ float sa[CHUNK], sdt[CHUNK], sdec[CHUNK];
    __shared__ __bf16 Xt[HEADDIM][136];   // [p][s] = xs*dt transposed
    __shared__ __bf16 Bt[DSTATE][136];    // [n][s] = B transposed
    const int row0 = b * SEQ + c * CHUNK;
    const int bc = b * NCHUNK + c;
    const float Ah = -__expf(A_log[h]);
    const float Dh = Dp[h];
    if (tid < CHUNK) {
        float d = dtb[(size_t)(row0 + tid) * NHEADS + h];
        sdt[tid] = d;
        sa[tid] = d * Ah;
    }
    __syncthreads();
    for (int off = 1; off < CHUNK; off <<= 1) {
        float v = 0.f;
        if (tid < CHUNK && tid >= off) v = sa[tid - off];
        __syncthreads();
        if (tid < CHUNK) sa[tid] += v;
        __syncthreads();
    }
    const float alast = sa[CHUNK - 1];
    if (tid < CHUNK) sdec[tid] = __expf(alast - sa[tid]);
    __syncthreads();
    {
        const int s = tid >> 1;
        const float dts = sdt[s];
        #pragma unroll
        for (int li = 0; li < 4; ++li) {
            int p0 = (tid & 1) * 8 + li * 16;
            bf16x8 v = *(const bf16x8*)(xs + (size_t)(row0 + s) * DINNER + h * HEADDIM + p0);
            #pragma unroll
            for (int i = 0; i < 8; ++i) Xt[p0 + i][s] = (__bf16)((float)v[i] * dts);
        }
        #pragma unroll
        for (int li = 0; li < 8; ++li) {
            int n0 = (tid & 1) * 8 + li * 16;
            bf16x8 v = *(const bf16x8*)(Bm + (size_t)(row0 + s) * DSTATE + n0);
            #pragma unroll
            for (int i = 0; i < 8; ++i) Bt[n0 + i][s] = v[i];
        }
    }
    __syncthreads();
    // ---- phase C: Y_diag = (L∘G)·X. mfma(X_frag_p, W_frag_q) -> D rows=p, cols=q
    __builtin_amdgcn_s_setprio(1);
    {
        const int q0 = w * 32;
        f32x4 acc[4][2] = {};   // [pf][fr]
        #pragma unroll
        for (int kc = 0; kc < 4; ++kc) {
            const int sbase = kc * 32 + lk * 8;
            bf16x8 av[2];
            #pragma unroll
            for (int fr = 0; fr < 2; ++fr) {
                int q = q0 + fr * 16 + lq;
                bf16x8 g = *(const bf16x8*)(G + ((size_t)bc * CHUNK + q) * CHUNK + sbase);
                float saq = sa[q];
                bf16x8 wv;
                #pragma unroll
                for (int j = 0; j < 8; ++j) {
                    int s = sbase + j;
                    float val = (s <= q) ? __expf(saq - sa[s]) * (float)g[j] : 0.f;
                    wv[j] = (__bf16)val;
                }
                av[fr] = wv;
            }
            #pragma unroll
            for (int pf = 0; pf < 4; ++pf) {
                bf16x8 xv = *(const bf16x8*)&Xt[pf * 16 + lq][sbase];
                #pragma unroll
                for (int fr = 0; fr < 2; ++fr)
                    acc[pf][fr] = __builtin_amdgcn_mfma_f32_16x16x32_bf16(xv, av[fr], acc[pf][fr], 0, 0, 0);
            }
        }
        #pragma unroll
        for (int fr = 0; fr < 2; ++fr)
            #pragma unroll
            for (int pf = 0; pf < 4; ++pf) {
                int q = q0 + fr * 16 + lq;
                int p = pf * 16 + lk * 4;
                size_t idx = (size_t)(row0 + q) * DINNER + h * HEADDIM + p;
                us4 xv4 = *(const us4*)(xs + idx);   // read original before write (y==xs alias)
                f32x4 a = acc[pf][fr];
                us4 o = { f2bf_bits(a[0] + Dh * bfbits2f(xv4.a)),
                          f2bf_bits(a[1] + Dh * bfbits2f(xv4.b)),
                          f2bf_bits(a[2] + Dh * bfbits2f(xv4.c)),
                          f2bf_bits(a[3] + Dh * bfbits2f(xv4.d)) };
                *(us4*)(y + idx) = o;
            }
    }
    // ---- phase D: states = (X*dec)·B^T. mfma(B_frag_n, Xdec_frag_p) -> D rows=n, cols=p
    {
        const int n0 = w * 32;
        f32x4 acc[2][4] = {};   // [nf][pf]
        #pragma unroll
        for (int kc = 0; kc < 4; ++kc) {
            const int sbase = kc * 32 + lk * 8;
            bf16x8 xd[4];
            #pragma unroll
            for (int pf = 0; pf < 4; ++pf) {
                bf16x8 xv = *(const bf16x8*)&Xt[pf * 16 + lq][sbase];
                bf16x8 sc;
                #pragma unroll
                for (int j = 0; j < 8; ++j) sc[j] = (__bf16)((float)xv[j] * sdec[sbase + j]);
                xd[pf] = sc;
            }
            #pragma unroll
            for (int nf = 0; nf < 2; ++nf) {
                bf16x8 bb = *(const bf16x8*)&Bt[n0 + nf * 16 + lq][sbase];
                #pragma unroll
                for (int pf = 0; pf < 4; ++pf)
                    acc[nf][pf] = __builtin_amdgcn_mfma_f32_16x16x32_bf16(bb, xd[pf], acc[nf][pf], 0, 0, 0);
            }
        }
        __builtin_amdgcn_s_setprio(0);
        const size_t sb = ((size_t)bc * NHEADS + h) * (HEADDIM * DSTATE);
        #pragma unroll
        for (int nf = 0; nf < 2; ++nf)
            #pragma unroll
            for (int pf = 0; pf < 4; ++pf) {
                int p = pf * 16 + lq;
                int n = n0 + nf * 16 + lk * 4;
                *(us4*)(states + sb + (size_t)p * DSTATE + n) = pack4(acc[nf][pf]);
            }
    }
    if (tid == 0) asum[bc * NHEADS + h] = alast;
}

// ================= kernel 5: inter-chunk sequential scan (16 segments, prefetched) =================
__global__ __launch_bounds__(256) void k_scan(bf16* __restrict__ states, const float* __restrict__ asum)
{
    const int h = blockIdx.x, b = blockIdx.y, seg = blockIdx.z;
    const int e0 = seg * 512 + threadIdx.x;
    constexpr size_t CSTRIDE = (size_t)NHEADS * (HEADDIM * DSTATE);   // per-chunk stride
    const size_t base = ((size_t)(b * NCHUNK) * NHEADS + h) * (HEADDIM * DSTATE);
    float P0 = 0.f, P1 = 0.f;
    // prefetch chunk 0
    bf16 c0 = states[base + e0];
    bf16 c1 = states[base + e0 + 256];
    float dec = __expf(asum[(b * NCHUNK) * NHEADS + h]);
    for (int c = 0; c < NCHUNK; ++c) {
        const size_t cur = base + (size_t)c * CSTRIDE;
        bf16 n0, n1; float decn = dec;
        if (c + 1 < NCHUNK) {                       // issue next-chunk loads before current store/FMA
            n0 = states[cur + CSTRIDE + e0];
            n1 = states[cur + CSTRIDE + e0 + 256];
            decn = __expf(asum[(b * NCHUNK + c + 1) * NHEADS + h]);
        }
        float s0 = __bfloat162float(c0), s1 = __bfloat162float(c1);
        states[cur + e0]       = __float2bfloat16(P0);   // write prev-state
        states[cur + e0 + 256] = __float2bfloat16(P1);
        P0 = dec * P0 + s0;
        P1 = dec * P1 + s1;
        c0 = n0; c1 = n1; dec = decn;
    }
}

// ================= kernel 6: MFMA y += exp(a_cs) * C · prev^T, vectorized RMW =================
__global__ __launch_bounds__(256) void k_yoff(
    const bf16* __restrict__ Cm,
    const float* __restrict__ dtb, const float* __restrict__ A_log,
    const bf16* __restrict__ states,
    bf16* __restrict__ y)
{
    const int h = blockIdx.x, c = blockIdx.y, b = blockIdx.z;
    const int tid = threadIdx.x;
    const int l = tid & 63, w = tid >> 6;
    const int lq = l & 15, lk = l >> 4;
    __shared__ float sa[CHUNK];
    const int row0 = b * SEQ + c * CHUNK;
    const int bc = b * NCHUNK + c;
    const float Ah = -__expf(A_log[h]);
    if (tid < CHUNK) {
        float d = dtb[(size_t)(row0 + tid) * NHEADS + h];
        sa[tid] = d * Ah;
    }
    __syncthreads();
    for (int off = 1; off < CHUNK; off <<= 1) {
        float v = 0.f;
        if (tid < CHUNK && tid >= off) v = sa[tid - off];
        __syncthreads();
        if (tid < CHUNK) sa[tid] += v;
        __syncthreads();
    }
    const size_t sb = ((size_t)bc * NHEADS + h) * (HEADDIM * DSTATE);
    const int q0 = w * 32;
    f32x4 acc[4][2] = {};   // [fc(p)][fr(q)]
    #pragma unroll
    for (int kc = 0; kc < 4; ++kc) {
        const int nbase = kc * 32 + lk * 8;
        bf16x8 av[2], bv[4];
        #pragma unroll
        for (int fr = 0; fr < 2; ++fr)
            av[fr] = *(const bf16x8*)(Cm + (size_t)(row0 + q0 + fr * 16 + lq) * DSTATE + nbase);
        #pragma unroll
        for (int fc = 0; fc < 4; ++fc)
            bv[fc] = *(const bf16x8*)(states + sb + (size_t)(fc * 16 + lq) * DSTATE + nbase);
        #pragma unroll
        for (int fc = 0; fc < 4; ++fc)
            #pragma unroll
            for (int fr = 0; fr < 2; ++fr)
                acc[fc][fr] = __builtin_amdgcn_mfma_f32_16x16x32_bf16(bv[fc], av[fr], acc[fc][fr], 0, 0, 0);
    }
    #pragma unroll
    for (int fr = 0; fr < 2; ++fr)
        #pragma unroll
        for (int fc = 0; fc < 4; ++fc) {
            int q = q0 + fr * 16 + lq;
            int p = fc * 16 + lk * 4;
            size_t idx = (size_t)(row0 + q) * DINNER + h * HEADDIM + p;
            const float eq = __expf(sa[q]);
            us4 cur = *(const us4*)(y + idx);
            f32x4 a = acc[fc][fr];
            us4 o = { f2bf_bits(bfbits2f(cur.a) + eq * a[0]),
                      f2bf_bits(bfbits2f(cur.b) + eq * a[1]),
                      f2bf_bits(bfbits2f(cur.c) + eq * a[2]),
                      f2bf_bits(bfbits2f(cur.d) + eq * a[3]) };
            *(us4*)(y + idx) = o;
        }
}

// ================= kernel 7: gated RMSNorm -> bf16 g (g aliases z; vectorized) =================
__global__ __launch_bounds__(256) void k_norm(
    const bf16* __restrict__ y, const bf16* __restrict__ z,
    const float* __restrict__ norm_w, bf16* __restrict__ g)
{
    const int tid = threadIdx.x;
    const int tk = tid >> 7;             // token within block
    const int lane = tid & 127;
    const int m = blockIdx.x * 2 + tk;
    const int e0 = lane * 8;
    bf16x8 z8 = *(const bf16x8*)(z + (size_t)m * DINNER + e0);
    bf16x8 y8 = *(const bf16x8*)(y + (size_t)m * DINNER + e0);
    float gg[8];
    float ss = 0.f;
    #pragma unroll
    for (int i = 0; i < 8; ++i) {
        float zz = (float)z8[i];
        gg[i] = (float)y8[i] * (zz * sigmoidf_(zz));
        ss += gg[i] * gg[i];
    }
    #pragma unroll
    for (int o = 32; o > 0; o >>= 1) ss += __shfl_xor(ss, o, 64);
    __shared__ float red[4];
    if ((tid & 63) == 0) red[tid >> 6] = ss;
    __syncthreads();
    const float scale = rsqrtf((red[tk * 2] + red[tk * 2 + 1]) / DINNER + 1e-5f);
    const float4 nw0 = *(const float4*)(norm_w + e0);
    const float4 nw1 = *(const float4*)(norm_w + e0 + 4);
    bf16x8 o8;
    o8[0] = (__bf16)(gg[0] * scale * nw0.x);
    o8[1] = (__bf16)(gg[1] * scale * nw0.y);
    o8[2] = (__bf16)(gg[2] * scale * nw0.z);
    o8[3] = (__bf16)(gg[3] * scale * nw0.w);
    o8[4] = (__bf16)(gg[4] * scale * nw1.x);
    o8[5] = (__bf16)(gg[5] * scale * nw1.y);
    o8[6] = (__bf16)(gg[6] * scale * nw1.z);
    o8[7] = (__bf16)(gg[7] * scale * nw1.w);
    *(bf16x8*)(g + (size_t)m * DINNER + e0) = o8;
}

// ================= launch =================
extern "C" void kernel_launch(void* const* d_in, const int* in_sizes, int n_in,
                              void* d_out, int out_size, void* d_ws, size_t ws_size,
                              hipStream_t stream) {
    const float* x       = (const float*)d_in[0];
    const float* W_in    = (const float*)d_in[1];
    const float* conv_w  = (const float*)d_in[2];
    const float* conv_b  = (const float*)d_in[3];
    const float* dt_bias = (const float*)d_in[4];
    const float* A_log   = (const float*)d_in[5];
    const float* Dp      = (const float*)d_in[6];
    const float* norm_w  = (const float*)d_in[7];
    const float* W_out   = (const float*)d_in[8];
    float* out = (float*)d_out;

    if (ws_size < WS_NEED) {
        k_sentinel<<<1, 1, 0, stream>>>(out);
        return;
    }

    char* ws = (char*)d_ws;
    bf16* z     = (bf16*)(ws + OFF_Z);
    bf16* gb    = (bf16*)(ws + OFF_Z);    // g aliases z
    bf16* xbc   = (bf16*)(ws + OFF_XBC);
    bf16* st    = (bf16*)(ws + OFF_XBC);  // states alias xbc
    float* dtb  = (float*)(ws + OFF_DT);
    bf16* xs    = (bf16*)(ws + OFF_XS);
    bf16* yb    = (bf16*)(ws + OFF_XS);   // y aliases xs
    bf16* xb    = (bf16*)(ws + OFF_XS);   // bf16 x, dead before k_conv writes xs
    bf16* Bm    = (bf16*)(ws + OFF_B);
    bf16* Wbin  = (bf16*)(ws + OFF_B);    // bf16 W_in (padded), dead before k_conv writes Bm
    bf16* Cm    = (bf16*)(ws + OFF_C);
    bf16* G     = (bf16*)(ws + OFF_G);
    bf16* Wbout = (bf16*)(ws + OFF_G);    // bf16 W_out, cast after k_ssd consumed G
    float* asum = (float*)(ws + OFF_ASUM);

    k_cast_front<<<(NX4 + NW4 + 255) / 256, 256, 0, stream>>>(x, W_in, xb, Wbin);
    k_gemm_in<<<dim3(NPAD / 128, MTOT / 128), 256, 0, stream>>>(xb, Wbin, dt_bias, z, xbc, dtb);
    k_conv<<<MTOT / CTOK, 320, 0, stream>>>(xbc, conv_w, conv_b, xs, Bm, Cm);
    k_gmat<<<dim3(2, 2, BSZ * NCHUNK), 64, 0, stream>>>(Cm, Bm, G);
    k_ssd<<<dim3(NHEADS, NCHUNK, BSZ), 256, 0, stream>>>(xs, Bm, dtb, A_log, Dp, G, yb, st, asum);
    k_cast_x<<<(DMODEL * DINNER / 4 + 255) / 256, 256, 0, stream>>>(W_out, Wbout, DMODEL * DINNER / 4);
    k_scan<<<dim3(NHEADS, BSZ, 16), 256, 0, stream>>>(st, asum);
    k_yoff<<<dim3(NHEADS, NCHUNK, BSZ), 256, 0, stream>>>(Cm, dtb, A_log, st, yb);
    k_norm<<<MTOT / 2, 256, 0, stream>>>(yb, z, norm_w, gb);
    k_gemm_out<<<dim3(DMODEL / 128, MTOT / 128), 256, 0, stream>>>(gb, Wbout, x, out);
}

// Round 14
// 265.507 us; speedup vs baseline: 1.0114x; 1.0114x over previous
//
#include <hip/hip_runtime.h>
#include <hip/hip_bf16.h>

typedef __hip_bfloat16 bf16;
typedef __attribute__((ext_vector_type(8))) __bf16 bf16x8;
typedef __attribute__((ext_vector_type(4))) float f32x4;

// ---------------- problem constants ----------------
constexpr int BSZ = 4, SEQ = 4096, DMODEL = 512;
constexpr int DSTATE = 128, HEADDIM = 64, DINNER = 1024, NHEADS = 16, CHUNK = 128;
constexpr int CONVDIM = DINNER + 2 * DSTATE;              // 1280
constexpr int DINPROJ = 2 * DINNER + 2 * DSTATE + NHEADS; // 2320
constexpr int NPAD = 2432;                                // 19*128, padded N for in_proj
constexpr int MTOT = BSZ * SEQ;                           // 16384
constexpr int NCHUNK = SEQ / CHUNK;                       // 32

// ---------------- workspace layout (bytes) ----------------
constexpr size_t OFF_Z    = 0;                                               // bf16 [MTOT][DINNER]
constexpr size_t OFF_XBC  = OFF_Z    + (size_t)MTOT * DINNER * 2;            // bf16 [MTOT][CONVDIM]
constexpr size_t OFF_DT   = OFF_XBC  + (size_t)MTOT * CONVDIM * 2;           // f32  [MTOT][NHEADS]
constexpr size_t OFF_XS   = OFF_DT   + (size_t)MTOT * NHEADS * 4;            // bf16 [MTOT][DINNER]
constexpr size_t OFF_B    = OFF_XS   + (size_t)MTOT * DINNER * 2;            // bf16 [MTOT][DSTATE]
constexpr size_t OFF_C    = OFF_B    + (size_t)MTOT * DSTATE * 2;            // bf16 [MTOT][DSTATE]
constexpr size_t OFF_G    = OFF_C    + (size_t)MTOT * DSTATE * 2;            // bf16 [B*NC][128][128]
constexpr size_t OFF_ASUM = OFF_G    + (size_t)BSZ * NCHUNK * CHUNK * CHUNK * 2; // f32
constexpr size_t WS_NEED  = OFF_ASUM + 8192;                                 // ~117MiB

static __device__ __forceinline__ float sigmoidf_(float x) { return 1.f / (1.f + __expf(-x)); }
static __device__ __forceinline__ unsigned short f2bf_bits(float f) {
    __hip_bfloat16 h = __float2bfloat16(f);
    return *reinterpret_cast<unsigned short*>(&h);
}
static __device__ __forceinline__ float bfbits2f(unsigned short u) {
    return __bfloat162float(*reinterpret_cast<bf16*>(&u));
}
struct us4 { unsigned short a, b, c, d; };
static __device__ __forceinline__ us4 pack4(const f32x4 v) {
    return { f2bf_bits(v[0]), f2bf_bits(v[1]), f2bf_bits(v[2]), f2bf_bits(v[3]) };
}

__global__ void k_sentinel(float* out) { out[0] = 1.0e9f; }

// ================= cast kernels =================
__global__ __launch_bounds__(256) void k_cast_x(const float* __restrict__ in, bf16* __restrict__ out, int n4) {
    int i = blockIdx.x * 256 + threadIdx.x;
    if (i >= n4) return;
    float4 f = ((const float4*)in)[i];
    us4 v = { f2bf_bits(f.x), f2bf_bits(f.y), f2bf_bits(f.z), f2bf_bits(f.w) };
    ((us4*)out)[i] = v;
}

__global__ __launch_bounds__(256) void k_cast_win(const float* __restrict__ W, bf16* __restrict__ out) {
    int i = blockIdx.x * 256 + threadIdx.x;
    if (i >= NPAD * (DMODEL / 4)) return;
    int row = i / (DMODEL / 4);
    us4 v;
    if (row < DINPROJ) {
        float4 f = ((const float4*)W)[i];
        v = { f2bf_bits(f.x), f2bf_bits(f.y), f2bf_bits(f.z), f2bf_bits(f.w) };
    } else {
        v = { 0, 0, 0, 0 };
    }
    ((us4*)out)[i] = v;
}

// ================= MFMA GEMM core: R5/R10 proven config (85us measured, best of 5 variants) =================
// 3-buf BK=32, BOTH A and B staged via inverse-swizzled global_load_lds, vmcnt(4).
// 128x128 tile, 4 waves (2x2). LDS per buffer: 64 rows x 128B holding 128 tile rows
// as 2 half-rows; logical chunk L = phys ^ (row&7); tile row = (L>>2)*64 + row.
typedef const __attribute__((address_space(1))) void* gas_t;
typedef __attribute__((address_space(3))) void* las_t;
static __device__ __forceinline__ void gload_lds16(const void* g, void* l) {
    __builtin_amdgcn_global_load_lds((gas_t)g, (las_t)l, 16, 0, 0);
}

template<int K>
static __device__ __forceinline__ void gemm_core(
    const bf16* __restrict__ A, const bf16* __restrict__ B,
    int m0, int n0, bf16* ldsA, bf16* ldsB, f32x4 acc[4][4])
{
    constexpr int NT = K / 32;
    const int tid = threadIdx.x;
    const int l = tid & 63, w = tid >> 6;
    const int wr = w >> 1, wc = w & 1;
    const int lq = l & 15, lk = l >> 4;

    auto stage = [&](int buf, int t) {
        const int k0 = t * 32;
        #pragma unroll
        for (int i = 0; i < 2; ++i) {
            int q = w * 16 + i * 8 + (l >> 3);   // LDS row [0,64)
            int p = l & 7;                        // phys 16B chunk
            int L = p ^ (q & 7);                  // logical chunk
            int ra = (L >> 2) * 64 + q;           // tile row [0,128)
            int ck = L & 3;                       // k-chunk (8 bf16)
            gload_lds16(A + (size_t)(m0 + ra) * K + k0 + ck * 8,
                        ldsA + buf * 4096 + (w * 16 + i * 8) * 64);
            gload_lds16(B + (size_t)(n0 + ra) * K + k0 + ck * 8,
                        ldsB + buf * 4096 + (w * 16 + i * 8) * 64);
        }
    };

    stage(0, 0);
    stage(1, 1);
    for (int t = 0; t < NT; ++t) {
        if (t + 1 < NT) asm volatile("s_waitcnt vmcnt(4)" ::: "memory");
        else            asm volatile("s_waitcnt vmcnt(0)" ::: "memory");
        __builtin_amdgcn_s_barrier();
        __builtin_amdgcn_sched_barrier(0);
        if (t + 2 < NT) stage((t + 2) % 3, t + 2);
        const int buf = t % 3;
        bf16x8 av[4], bv[4];
        #pragma unroll
        for (int f = 0; f < 4; ++f) {
            int ra = wr * 64 + f * 16 + lq;
            int qa = ra & 63, La = (ra >> 6) * 4 + lk, pa = La ^ (qa & 7);
            av[f] = *(const bf16x8*)(ldsA + buf * 4096 + qa * 64 + pa * 8);
            int rb = wc * 64 + f * 16 + lq;
            int qb = rb & 63, Lb = (rb >> 6) * 4 + lk, pb = Lb ^ (qb & 7);
            bv[f] = *(const bf16x8*)(ldsB + buf * 4096 + qb * 64 + pb * 8);
        }
        // swapped operands: D rows = n (B rows), cols = m -> acc[nf][mf]
        #pragma unroll
        for (int nf = 0; nf < 4; ++nf)
            #pragma unroll
            for (int mf = 0; mf < 4; ++mf)
                acc[nf][mf] = __builtin_amdgcn_mfma_f32_16x16x32_bf16(bv[nf], av[mf], acc[nf][mf], 0, 0, 0);
    }
}

static __device__ __forceinline__ void swz_block(int& bx, int& by) {
    int gx = gridDim.x;
    int nwg = gx * gridDim.y;
    int wg = by * gx + bx;
    int q = nwg >> 3;                    // nwg % 8 == 0 in all uses (bijective)
    wg = (wg & 7) * q + (wg >> 3);
    bx = wg % gx; by = wg / gx;
}

// ================= kernel 1: in_proj MFMA GEMM + split + softplus(dt) =================
__global__ __launch_bounds__(256) void k_gemm_in(
    const bf16* __restrict__ xb, const bf16* __restrict__ Wb,
    const float* __restrict__ dt_bias,
    bf16* __restrict__ z, bf16* __restrict__ xbc, float* __restrict__ dtb)
{
    __shared__ bf16 ldsA[3 * 4096];
    __shared__ bf16 ldsB[3 * 4096];
    int bx = blockIdx.x, by = blockIdx.y;
    swz_block(bx, by);
    const int m0 = by * 128, n0 = bx * 128;
    f32x4 acc[4][4] = {};
    gemm_core<DMODEL>(xb, Wb, m0, n0, ldsA, ldsB, acc);
    const int l = threadIdx.x & 63, w = threadIdx.x >> 6;
    const int wr = w >> 1, wc = w & 1, lq = l & 15, lk = l >> 4;
    const int mg = m0 + wr * 64, ng = n0 + wc * 64;
    if (n0 < DINNER) {                       // whole tile in z
        #pragma unroll
        for (int nf = 0; nf < 4; ++nf)
            #pragma unroll
            for (int mf = 0; mf < 4; ++mf) {
                int n = ng + nf * 16 + lk * 4;
                int m = mg + mf * 16 + lq;
                *(us4*)(z + (size_t)m * DINNER + n) = pack4(acc[nf][mf]);
            }
    } else if (n0 < DINNER + CONVDIM) {      // whole tile in xbc
        #pragma unroll
        for (int nf = 0; nf < 4; ++nf)
            #pragma unroll
            for (int mf = 0; mf < 4; ++mf) {
                int n = ng + nf * 16 + lk * 4 - DINNER;
                int m = mg + mf * 16 + lq;
                *(us4*)(xbc + (size_t)m * CONVDIM + n) = pack4(acc[nf][mf]);
            }
    } else {                                 // dt block (+ zero pad)
        #pragma unroll
        for (int nf = 0; nf < 4; ++nf)
            #pragma unroll
            for (int mf = 0; mf < 4; ++mf)
                #pragma unroll
                for (int j = 0; j < 4; ++j) {
                    int n = ng + nf * 16 + lk * 4 + j;
                    int m = mg + mf * 16 + lq;
                    if (n < DINPROJ) {
                        int h = n - (DINNER + CONVDIM);
                        float t = acc[nf][mf][j] + dt_bias[h];
                        dtb[(size_t)m * NHEADS + h] = (t > 20.f) ? t : log1pf(__expf(t));
                    }
                }
    }
}

// ================= kernel 8: out_proj MFMA GEMM + residual =================
__global__ __launch_bounds__(256) void k_gemm_out(
    const bf16* __restrict__ gb, const bf16* __restrict__ Wb,
    const float* __restrict__ xres, float* __restrict__ outp)
{
    __shared__ bf16 ldsA[3 * 4096];
    __shared__ bf16 ldsB[3 * 4096];
    int bx = blockIdx.x, by = blockIdx.y;
    swz_block(bx, by);
    const int m0 = by * 128, n0 = bx * 128;
    f32x4 acc[4][4] = {};
    gemm_core<DINNER>(gb, Wb, m0, n0, ldsA, ldsB, acc);
    const int l = threadIdx.x & 63, w = threadIdx.x >> 6;
    const int wr = w >> 1, wc = w & 1, lq = l & 15, lk = l >> 4;
    const int mg = m0 + wr * 64, ng = n0 + wc * 64;
    #pragma unroll
    for (int nf = 0; nf < 4; ++nf)
        #pragma unroll
        for (int mf = 0; mf < 4; ++mf) {
            int n = ng + nf * 16 + lk * 4;
            int m = mg + mf * 16 + lq;
            float4 r = *(const float4*)(xres + (size_t)m * DMODEL + n);
            float4 o = { r.x + acc[nf][mf][0], r.y + acc[nf][mf][1],
                         r.z + acc[nf][mf][2], r.w + acc[nf][mf][3] };
            *(float4*)(outp + (size_t)m * DMODEL + n) = o;
        }
}

// ================= kernel 2: causal depthwise conv(K=4) + SiLU + split =================
constexpr int CTOK = 8;
__global__ __launch_bounds__(320) void k_conv(
    const bf16* __restrict__ xbc, const float* __restrict__ cw, const float* __restrict__ cb,
    bf16* __restrict__ xs, bf16* __restrict__ Bm, bf16* __restrict__ Cm)
{
    const int m0 = blockIdx.x * CTOK;     // never crosses batch boundary (4096 % 8 == 0)
    const int c4 = threadIdx.x;           // [0,320)
    const int c = c4 * 4;
    const int l0 = m0 & 4095;
    float4 cbv = ((const float4*)cb)[c4];
    const float4 w0 = ((const float4*)cw)[c + 0];
    const float4 w1 = ((const float4*)cw)[c + 1];
    const float4 w2 = ((const float4*)cw)[c + 2];
    const float4 w3 = ((const float4*)cw)[c + 3];
    us4 rows[CTOK + 3];
    #pragma unroll
    for (int t = -3; t < CTOK; ++t) {
        int ll = l0 + t;
        if (ll >= 0) rows[t + 3] = *(const us4*)(xbc + (size_t)(m0 + t) * CONVDIM + c);
        else         rows[t + 3] = { 0, 0, 0, 0 };
    }
    #pragma unroll
    for (int t = 0; t < CTOK; ++t) {
        float a0 = cbv.x, a1 = cbv.y, a2 = cbv.z, a3 = cbv.w;
        #pragma unroll
        for (int k = 0; k < 4; ++k) {
            us4 v = rows[t + k];
            a0 += bfbits2f(v.a) * ((const float*)&w0)[k];
            a1 += bfbits2f(v.b) * ((const float*)&w1)[k];
            a2 += bfbits2f(v.c) * ((const float*)&w2)[k];
            a3 += bfbits2f(v.d) * ((const float*)&w3)[k];
        }
        us4 o = { f2bf_bits(a0 * sigmoidf_(a0)), f2bf_bits(a1 * sigmoidf_(a1)),
                  f2bf_bits(a2 * sigmoidf_(a2)), f2bf_bits(a3 * sigmoidf_(a3)) };
        int m = m0 + t;
        if (c < DINNER)               *(us4*)(xs + (size_t)m * DINNER + c) = o;
        else if (c < DINNER + DSTATE) *(us4*)(Bm + (size_t)m * DSTATE + (c - DINNER)) = o;
        else                          *(us4*)(Cm + (size_t)m * DSTATE + (c - DINNER - DSTATE)) = o;
    }
}

// ================= kernel 3: MFMA G = C · B^T per (b,chunk), vectorized stores =================
__global__ __launch_bounds__(64) void k_gmat(
    const bf16* __restrict__ Cm, const bf16* __restrict__ Bm, bf16* __restrict__ G)
{
    const int bc = blockIdx.z;
    const int q0 = blockIdx.x * 64, s0 = blockIdx.y * 64;
    const int row0 = bc * CHUNK;
    const int l = threadIdx.x;
    const int lq = l & 15, lk = l >> 4;
    f32x4 acc[4][4] = {};   // [fs][fq]
    #pragma unroll
    for (int kc = 0; kc < 4; ++kc) {
        bf16x8 av[4], bv[4];
        #pragma unroll
        for (int f = 0; f < 4; ++f) {
            av[f] = *(const bf16x8*)(Cm + (size_t)(row0 + q0 + f * 16 + lq) * DSTATE + kc * 32 + lk * 8);
            bv[f] = *(const bf16x8*)(Bm + (size_t)(row0 + s0 + f * 16 + lq) * DSTATE + kc * 32 + lk * 8);
        }
        #pragma unroll
        for (int fs = 0; fs < 4; ++fs)
            #pragma unroll
            for (int fq = 0; fq < 4; ++fq)
                acc[fs][fq] = __builtin_amdgcn_mfma_f32_16x16x32_bf16(bv[fs], av[fq], acc[fs][fq], 0, 0, 0);
    }
    #pragma unroll
    for (int fs = 0; fs < 4; ++fs)
        #pragma unroll
        for (int fq = 0; fq < 4; ++fq) {
            int q = q0 + fq * 16 + lq;
            int s = s0 + fs * 16 + lk * 4;
            *(us4*)(G + ((size_t)bc * CHUNK + q) * CHUNK + s) = pack4(acc[fs][fq]);
        }
}

// ================= kernel 4: MFMA SSD per (b,c,h): y = (L∘G)·X + D*xs ; states =================
__global__ __launch_bounds__(256) void k_ssd(
    const bf16* __restrict__ xs /* == y */, const bf16* __restrict__ Bm,
    const float* __restrict__ dtb, const float* __restrict__ A_log,
    const float* __restrict__ Dp, const bf16* __restrict__ G,
    bf16* __restrict__ y, bf16* __restrict__ states, float* __restrict__ asum)
{
    const int h = blockIdx.x, c = blockIdx.y, b = blockIdx.z;
    const int tid = threadIdx.x;
    const int l = tid & 63, w = tid >> 6;
    const int lq = l & 15, lk = l >> 4;
    __shared__ float sa[CHUNK], sdt[CHUNK], sdec[CHUNK];
    __shared__ __bf16 Xt[HEADDIM][136];   // [p][s] = xs*dt transposed
    __shared__ __bf16 Bt[DSTATE][136];    // [n][s] = B transposed
    const int row0 = b * SEQ + c * CHUNK;
    const int bc = b * NCHUNK + c;
    const float Ah = -__expf(A_log[h]);
    const float Dh = Dp[h];
    if (tid < CHUNK) {
        float d = dtb[(size_t)(row0 + tid) * NHEADS + h];
        sdt[tid] = d;
        sa[tid] = d * Ah;
    }
    __syncthreads();
    for (int off = 1; off < CHUNK; off <<= 1) {
        float v = 0.f;
        if (tid < CHUNK && tid >= off) v = sa[tid - off];
        __syncthreads();
        if (tid < CHUNK) sa[tid] += v;
        __syncthreads();
    }
    const float alast = sa[CHUNK - 1];
    if (tid < CHUNK) sdec[tid] = __expf(alast - sa[tid]);
    __syncthreads();
    {
        const int s = tid >> 1;
        const float dts = sdt[s];
        #pragma unroll
        for (int li = 0; li < 4; ++li) {
            int p0 = (tid & 1) * 8 + li * 16;
            bf16x8 v = *(const bf16x8*)(xs + (size_t)(row0 + s) * DINNER + h * HEADDIM + p0);
            #pragma unroll
            for (int i = 0; i < 8; ++i) Xt[p0 + i][s] = (__bf16)((float)v[i] * dts);
        }
        #pragma unroll
        for (int li = 0; li < 8; ++li) {
            int n0 = (tid & 1) * 8 + li * 16;
            bf16x8 v = *(const bf16x8*)(Bm + (size_t)(row0 + s) * DSTATE + n0);
            #pragma unroll
            for (int i = 0; i < 8; ++i) Bt[n0 + i][s] = v[i];
        }
    }
    __syncthreads();
    // ---- phase C: Y_diag = (L∘G)·X. mfma(X_frag_p, W_frag_q) -> D rows=p, cols=q
    __builtin_amdgcn_s_setprio(1);
    {
        const int q0 = w * 32;
        f32x4 acc[4][2] = {};   // [pf][fr]
        #pragma unroll
        for (int kc = 0; kc < 4; ++kc) {
            const int sbase = kc * 32 + lk * 8;
            bf16x8 av[2];
            #pragma unroll
            for (int fr = 0; fr < 2; ++fr) {
                int q = q0 + fr * 16 + lq;
                bf16x8 g = *(const bf16x8*)(G + ((size_t)bc * CHUNK + q) * CHUNK + sbase);
                float saq = sa[q];
                bf16x8 wv;
                #pragma unroll
                for (int j = 0; j < 8; ++j) {
                    int s = sbase + j;
                    float val = (s <= q) ? __expf(saq - sa[s]) * (float)g[j] : 0.f;
                    wv[j] = (__bf16)val;
                }
                av[fr] = wv;
            }
            #pragma unroll
            for (int pf = 0; pf < 4; ++pf) {
                bf16x8 xv = *(const bf16x8*)&Xt[pf * 16 + lq][sbase];
                #pragma unroll
                for (int fr = 0; fr < 2; ++fr)
                    acc[pf][fr] = __builtin_amdgcn_mfma_f32_16x16x32_bf16(xv, av[fr], acc[pf][fr], 0, 0, 0);
            }
        }
        #pragma unroll
        for (int fr = 0; fr < 2; ++fr)
            #pragma unroll
            for (int pf = 0; pf < 4; ++pf) {
                int q = q0 + fr * 16 + lq;
                int p = pf * 16 + lk * 4;
                size_t idx = (size_t)(row0 + q) * DINNER + h * HEADDIM + p;
                us4 xv4 = *(const us4*)(xs + idx);   // read original before write (y==xs alias)
                f32x4 a = acc[pf][fr];
                us4 o = { f2bf_bits(a[0] + Dh * bfbits2f(xv4.a)),
                          f2bf_bits(a[1] + Dh * bfbits2f(xv4.b)),
                          f2bf_bits(a[2] + Dh * bfbits2f(xv4.c)),
                          f2bf_bits(a[3] + Dh * bfbits2f(xv4.d)) };
                *(us4*)(y + idx) = o;
            }
    }
    // ---- phase D: states = (X*dec)·B^T. mfma(B_frag_n, Xdec_frag_p) -> D rows=n, cols=p
    {
        const int n0 = w * 32;
        f32x4 acc[2][4] = {};   // [nf][pf]
        #pragma unroll
        for (int kc = 0; kc < 4; ++kc) {
            const int sbase = kc * 32 + lk * 8;
            bf16x8 xd[4];
            #pragma unroll
            for (int pf = 0; pf < 4; ++pf) {
                bf16x8 xv = *(const bf16x8*)&Xt[pf * 16 + lq][sbase];
                bf16x8 sc;
                #pragma unroll
                for (int j = 0; j < 8; ++j) sc[j] = (__bf16)((float)xv[j] * sdec[sbase + j]);
                xd[pf] = sc;
            }
            #pragma unroll
            for (int nf = 0; nf < 2; ++nf) {
                bf16x8 bb = *(const bf16x8*)&Bt[n0 + nf * 16 + lq][sbase];
                #pragma unroll
                for (int pf = 0; pf < 4; ++pf)
                    acc[nf][pf] = __builtin_amdgcn_mfma_f32_16x16x32_bf16(bb, xd[pf], acc[nf][pf], 0, 0, 0);
            }
        }
        __builtin_amdgcn_s_setprio(0);
        const size_t sb = ((size_t)bc * NHEADS + h) * (HEADDIM * DSTATE);
        #pragma unroll
        for (int nf = 0; nf < 2; ++nf)
            #pragma unroll
            for (int pf = 0; pf < 4; ++pf) {
                int p = pf * 16 + lq;
                int n = n0 + nf * 16 + lk * 4;
                *(us4*)(states + sb + (size_t)p * DSTATE + n) = pack4(acc[nf][pf]);
            }
    }
    if (tid == 0) asum[bc * NHEADS + h] = alast;
}

// ================= kernel 5: inter-chunk sequential scan (16 segments) =================
__global__ __launch_bounds__(256) void k_scan(bf16* __restrict__ states, const float* __restrict__ asum)
{
    const int h = blockIdx.x, b = blockIdx.y, seg = blockIdx.z;
    const int e0 = seg * 512 + threadIdx.x;
    float P[2];
    P[0] = 0.f; P[1] = 0.f;
    for (int c = 0; c < NCHUNK; ++c) {
        size_t base = ((size_t)(b * NCHUNK + c) * NHEADS + h) * (HEADDIM * DSTATE);
        float dec = __expf(asum[(b * NCHUNK + c) * NHEADS + h]);
        #pragma unroll
        for (int j = 0; j < 2; ++j) {
            size_t e = base + e0 + j * 256;
            float sc = __bfloat162float(states[e]);
            states[e] = __float2bfloat16(P[j]);
            P[j] = dec * P[j] + sc;
        }
    }
}

// ================= kernel 6: MFMA y += exp(a_cs) * C · prev^T, vectorized RMW =================
__global__ __launch_bounds__(256) void k_yoff(
    const bf16* __restrict__ Cm,
    const float* __restrict__ dtb, const float* __restrict__ A_log,
    const bf16* __restrict__ states,
    bf16* __restrict__ y)
{
    const int h = blockIdx.x, c = blockIdx.y, b = blockIdx.z;
    const int tid = threadIdx.x;
    const int l = tid & 63, w = tid >> 6;
    const int lq = l & 15, lk = l >> 4;
    __shared__ float sa[CHUNK];
    const int row0 = b * SEQ + c * CHUNK;
    const int bc = b * NCHUNK + c;
    const float Ah = -__expf(A_log[h]);
    if (tid < CHUNK) {
        float d = dtb[(size_t)(row0 + tid) * NHEADS + h];
        sa[tid] = d * Ah;
    }
    __syncthreads();
    for (int off = 1; off < CHUNK; off <<= 1) {
        float v = 0.f;
        if (tid < CHUNK && tid >= off) v = sa[tid - off];
        __syncthreads();
        if (tid < CHUNK) sa[tid] += v;
        __syncthreads();
    }
    const size_t sb = ((size_t)bc * NHEADS + h) * (HEADDIM * DSTATE);
    const int q0 = w * 32;
    f32x4 acc[4][2] = {};   // [fc(p)][fr(q)]
    #pragma unroll
    for (int kc = 0; kc < 4; ++kc) {
        const int nbase = kc * 32 + lk * 8;
        bf16x8 av[2], bv[4];
        #pragma unroll
        for (int fr = 0; fr < 2; ++fr)
            av[fr] = *(const bf16x8*)(Cm + (size_t)(row0 + q0 + fr * 16 + lq) * DSTATE + nbase);
        #pragma unroll
        for (int fc = 0; fc < 4; ++fc)
            bv[fc] = *(const bf16x8*)(states + sb + (size_t)(fc * 16 + lq) * DSTATE + nbase);
        #pragma unroll
        for (int fc = 0; fc < 4; ++fc)
            #pragma unroll
            for (int fr = 0; fr < 2; ++fr)
                acc[fc][fr] = __builtin_amdgcn_mfma_f32_16x16x32_bf16(bv[fc], av[fr], acc[fc][fr], 0, 0, 0);
    }
    #pragma unroll
    for (int fr = 0; fr < 2; ++fr)
        #pragma unroll
        for (int fc = 0; fc < 4; ++fc) {
            int q = q0 + fr * 16 + lq;
            int p = fc * 16 + lk * 4;
            size_t idx = (size_t)(row0 + q) * DINNER + h * HEADDIM + p;
            const float eq = __expf(sa[q]);
            us4 cur = *(const us4*)(y + idx);
            f32x4 a = acc[fc][fr];
            us4 o = { f2bf_bits(bfbits2f(cur.a) + eq * a[0]),
                      f2bf_bits(bfbits2f(cur.b) + eq * a[1]),
                      f2bf_bits(bfbits2f(cur.c) + eq * a[2]),
                      f2bf_bits(bfbits2f(cur.d) + eq * a[3]) };
            *(us4*)(y + idx) = o;
        }
}

// ================= kernel 7: gated RMSNorm -> bf16 g (g aliases z; vectorized) =================
__global__ __launch_bounds__(256) void k_norm(
    const bf16* __restrict__ y, const bf16* __restrict__ z,
    const float* __restrict__ norm_w, bf16* __restrict__ g)
{
    const int tid = threadIdx.x;
    const int tk = tid >> 7;             // token within block
    const int lane = tid & 127;
    const int m = blockIdx.x * 2 + tk;
    const int e0 = lane * 8;
    bf16x8 z8 = *(const bf16x8*)(z + (size_t)m * DINNER + e0);
    bf16x8 y8 = *(const bf16x8*)(y + (size_t)m * DINNER + e0);
    float gg[8];
    float ss = 0.f;
    #pragma unroll
    for (int i = 0; i < 8; ++i) {
        float zz = (float)z8[i];
        gg[i] = (float)y8[i] * (zz * sigmoidf_(zz));
        ss += gg[i] * gg[i];
    }
    #pragma unroll
    for (int o = 32; o > 0; o >>= 1) ss += __shfl_xor(ss, o, 64);
    __shared__ float red[4];
    if ((tid & 63) == 0) red[tid >> 6] = ss;
    __syncthreads();
    const float scale = rsqrtf((red[tk * 2] + red[tk * 2 + 1]) / DINNER + 1e-5f);
    const float4 nw0 = *(const float4*)(norm_w + e0);
    const float4 nw1 = *(const float4*)(norm_w + e0 + 4);
    bf16x8 o8;
    o8[0] = (__bf16)(gg[0] * scale * nw0.x);
    o8[1] = (__bf16)(gg[1] * scale * nw0.y);
    o8[2] = (__bf16)(gg[2] * scale * nw0.z);
    o8[3] = (__bf16)(gg[3] * scale * nw0.w);
    o8[4] = (__bf16)(gg[4] * scale * nw1.x);
    o8[5] = (__bf16)(gg[5] * scale * nw1.y);
    o8[6] = (__bf16)(gg[6] * scale * nw1.z);
    o8[7] = (__bf16)(gg[7] * scale * nw1.w);
    *(bf16x8*)(g + (size_t)m * DINNER + e0) = o8;
}

// ================= launch =================
extern "C" void kernel_launch(void* const* d_in, const int* in_sizes, int n_in,
                              void* d_out, int out_size, void* d_ws, size_t ws_size,
                              hipStream_t stream) {
    const float* x       = (const float*)d_in[0];
    const float* W_in    = (const float*)d_in[1];
    const float* conv_w  = (const float*)d_in[2];
    const float* conv_b  = (const float*)d_in[3];
    const float* dt_bias = (const float*)d_in[4];
    const float* A_log   = (const float*)d_in[5];
    const float* Dp      = (const float*)d_in[6];
    const float* norm_w  = (const float*)d_in[7];
    const float* W_out   = (const float*)d_in[8];
    float* out = (float*)d_out;

    if (ws_size < WS_NEED) {
        k_sentinel<<<1, 1, 0, stream>>>(out);
        return;
    }

    char* ws = (char*)d_ws;
    bf16* z     = (bf16*)(ws + OFF_Z);
    bf16* gb    = (bf16*)(ws + OFF_Z);    // g aliases z
    bf16* xbc   = (bf16*)(ws + OFF_XBC);
    bf16* st    = (bf16*)(ws + OFF_XBC);  // states alias xbc
    float* dtb  = (float*)(ws + OFF_DT);
    bf16* xs    = (bf16*)(ws + OFF_XS);
    bf16* yb    = (bf16*)(ws + OFF_XS);   // y aliases xs
    bf16* xb    = (bf16*)(ws + OFF_XS);   // bf16 x, dead before k_conv writes xs
    bf16* Bm    = (bf16*)(ws + OFF_B);
    bf16* Wbin  = (bf16*)(ws + OFF_B);    // bf16 W_in (padded), dead before k_conv writes Bm
    bf16* Cm    = (bf16*)(ws + OFF_C);
    bf16* G     = (bf16*)(ws + OFF_G);
    bf16* Wbout = (bf16*)(ws + OFF_G);    // bf16 W_out, cast after k_ssd consumed G
    float* asum = (float*)(ws + OFF_ASUM);

    k_cast_x<<<(MTOT * DMODEL / 4 + 255) / 256, 256, 0, stream>>>(x, xb, MTOT * DMODEL / 4);
    k_cast_win<<<(NPAD * DMODEL / 4 + 255) / 256, 256, 0, stream>>>(W_in, Wbin);
    k_gemm_in<<<dim3(NPAD / 128, MTOT / 128), 256, 0, stream>>>(xb, Wbin, dt_bias, z, xbc, dtb);
    k_conv<<<MTOT / CTOK, 320, 0, stream>>>(xbc, conv_w, conv_b, xs, Bm, Cm);
    k_gmat<<<dim3(2, 2, BSZ * NCHUNK), 64, 0, stream>>>(Cm, Bm, G);
    k_ssd<<<dim3(NHEADS, NCHUNK, BSZ), 256, 0, stream>>>(xs, Bm, dtb, A_log, Dp, G, yb, st, asum);
    k_cast_x<<<(DMODEL * DINNER / 4 + 255) / 256, 256, 0, stream>>>(W_out, Wbout, DMODEL * DINNER / 4);
    k_scan<<<dim3(NHEADS, BSZ, 16), 256, 0, stream>>>(st, asum);
    k_yoff<<<dim3(NHEADS, NCHUNK, BSZ), 256, 0, stream>>>(Cm, dtb, A_log, st, yb);
    k_norm<<<MTOT / 2, 256, 0, stream>>>(yb, z, norm_w, gb);
    k_gemm_out<<<dim3(DMODEL / 128, MTOT / 128), 256, 0, stream>>>(gb, Wbout, x, out);
}

// Round 15
// 260.193 us; speedup vs baseline: 1.0321x; 1.0204x over previous
//
#include <hip/hip_runtime.h>
#include <hip/hip_bf16.h>

typedef __hip_bfloat16 bf16;
typedef __attribute__((ext_vector_type(8))) __bf16 bf16x8;
typedef __attribute__((ext_vector_type(4))) float f32x4;

// ---------------- problem constants ----------------
constexpr int BSZ = 4, SEQ = 4096, DMODEL = 512;
constexpr int DSTATE = 128, HEADDIM = 64, DINNER = 1024, NHEADS = 16, CHUNK = 128;
constexpr int CONVDIM = DINNER + 2 * DSTATE;              // 1280
constexpr int DINPROJ = 2 * DINNER + 2 * DSTATE + NHEADS; // 2320
constexpr int NPAD = 2432;                                // 19*128, padded N for in_proj
constexpr int MTOT = BSZ * SEQ;                           // 16384
constexpr int NCHUNK = SEQ / CHUNK;                       // 32

// ---------------- workspace layout (bytes) ----------------
constexpr size_t OFF_Z    = 0;                                               // bf16 [MTOT][DINNER]
constexpr size_t OFF_XBC  = OFF_Z    + (size_t)MTOT * DINNER * 2;            // bf16 [MTOT][CONVDIM]
constexpr size_t OFF_DT   = OFF_XBC  + (size_t)MTOT * CONVDIM * 2;           // f32  [MTOT][NHEADS]
constexpr size_t OFF_XS   = OFF_DT   + (size_t)MTOT * NHEADS * 4;            // bf16 [MTOT][DINNER]
constexpr size_t OFF_B    = OFF_XS   + (size_t)MTOT * DINNER * 2;            // bf16 [MTOT][DSTATE]
constexpr size_t OFF_C    = OFF_B    + (size_t)MTOT * DSTATE * 2;            // bf16 [MTOT][DSTATE]
constexpr size_t OFF_G    = OFF_C    + (size_t)MTOT * DSTATE * 2;            // bf16 [B*NC][128][128]
constexpr size_t OFF_ASUM = OFF_G    + (size_t)BSZ * NCHUNK * CHUNK * CHUNK * 2; // f32
constexpr size_t WS_NEED  = OFF_ASUM + 8192;                                 // ~117MiB

static __device__ __forceinline__ float sigmoidf_(float x) { return 1.f / (1.f + __expf(-x)); }
static __device__ __forceinline__ unsigned short f2bf_bits(float f) {
    __hip_bfloat16 h = __float2bfloat16(f);
    return *reinterpret_cast<unsigned short*>(&h);
}
static __device__ __forceinline__ float bfbits2f(unsigned short u) {
    return __bfloat162float(*reinterpret_cast<bf16*>(&u));
}
struct us4 { unsigned short a, b, c, d; };
static __device__ __forceinline__ us4 pack4(const f32x4 v) {
    return { f2bf_bits(v[0]), f2bf_bits(v[1]), f2bf_bits(v[2]), f2bf_bits(v[3]) };
}

__global__ void k_sentinel(float* out) { out[0] = 1.0e9f; }

// ================= cast kernels =================
__global__ __launch_bounds__(256) void k_cast_x(const float* __restrict__ in, bf16* __restrict__ out, int n4) {
    int i = blockIdx.x * 256 + threadIdx.x;
    if (i >= n4) return;
    float4 f = ((const float4*)in)[i];
    us4 v = { f2bf_bits(f.x), f2bf_bits(f.y), f2bf_bits(f.z), f2bf_bits(f.w) };
    ((us4*)out)[i] = v;
}

__global__ __launch_bounds__(256) void k_cast_win(const float* __restrict__ W, bf16* __restrict__ out) {
    int i = blockIdx.x * 256 + threadIdx.x;
    if (i >= NPAD * (DMODEL / 4)) return;
    int row = i / (DMODEL / 4);
    us4 v;
    if (row < DINPROJ) {
        float4 f = ((const float4*)W)[i];
        v = { f2bf_bits(f.x), f2bf_bits(f.y), f2bf_bits(f.z), f2bf_bits(f.w) };
    } else {
        v = { 0, 0, 0, 0 };
    }
    ((us4*)out)[i] = v;
}

// ================= MFMA GEMM core: 8-wave variant of the R5 proven pipeline =================
// Same 128x128 tile, 3-buf BK=32, both operands via inverse-swizzled global_load_lds,
// counted vmcnt gate. 512 threads = 8 waves (2M x 4N), per-wave output 64x32.
// Doubles waves/CU (LDS still 48KB -> 3 blocks/CU = 24 waves) for latency hiding.
// LDS per buffer: 64 rows x 128B; logical chunk L = phys ^ (row&7);
// tile row = (L>>2)*64 + row; k-chunk = L&3.
// Stage: ONE gload per thread per operand; wave w covers LDS rows w*8..w*8+8
// (dest = wave-uniform base + lane*16B). Gate: vmcnt(2) (next stage's 2 loads in flight).
typedef const __attribute__((address_space(1))) void* gas_t;
typedef __attribute__((address_space(3))) void* las_t;
static __device__ __forceinline__ void gload_lds16(const void* g, void* l) {
    __builtin_amdgcn_global_load_lds((gas_t)g, (las_t)l, 16, 0, 0);
}

template<int K>
static __device__ __forceinline__ void gemm_core(
    const bf16* __restrict__ A, const bf16* __restrict__ B,
    int m0, int n0, bf16* ldsA, bf16* ldsB, f32x4 acc[2][4])
{
    constexpr int NT = K / 32;
    const int tid = threadIdx.x;           // [0,512)
    const int l = tid & 63, w = tid >> 6;  // 8 waves
    const int wr = w >> 2, wc = w & 3;     // 2M x 4N
    const int lq = l & 15, lk = l >> 4;

    auto stage = [&](int buf, int t) {
        const int k0 = t * 32;
        const int q = w * 8 + (l >> 3);      // LDS row [0,64)
        const int p = l & 7;                 // phys 16B chunk
        const int L = p ^ (q & 7);           // logical chunk
        const int ra = (L >> 2) * 64 + q;    // tile row [0,128)
        const int ck = L & 3;                // k-chunk (8 bf16)
        gload_lds16(A + (size_t)(m0 + ra) * K + k0 + ck * 8,
                    ldsA + buf * 4096 + w * 512);   // wave-uniform base + lane*16B
        gload_lds16(B + (size_t)(n0 + ra) * K + k0 + ck * 8,
                    ldsB + buf * 4096 + w * 512);
    };

    stage(0, 0);
    stage(1, 1);
    for (int t = 0; t < NT; ++t) {
        if (t + 1 < NT) asm volatile("s_waitcnt vmcnt(2)" ::: "memory");
        else            asm volatile("s_waitcnt vmcnt(0)" ::: "memory");
        __builtin_amdgcn_s_barrier();
        __builtin_amdgcn_sched_barrier(0);
        if (t + 2 < NT) stage((t + 2) % 3, t + 2);
        const int buf = t % 3;
        bf16x8 av[4], bv[2];
        #pragma unroll
        for (int f = 0; f < 4; ++f) {
            int ra = wr * 64 + f * 16 + lq;
            int qa = ra & 63, La = (ra >> 6) * 4 + lk, pa = La ^ (qa & 7);
            av[f] = *(const bf16x8*)(ldsA + buf * 4096 + qa * 64 + pa * 8);
        }
        #pragma unroll
        for (int f = 0; f < 2; ++f) {
            int rb = wc * 32 + f * 16 + lq;
            int qb = rb & 63, Lb = (rb >> 6) * 4 + lk, pb = Lb ^ (qb & 7);
            bv[f] = *(const bf16x8*)(ldsB + buf * 4096 + qb * 64 + pb * 8);
        }
        // swapped operands: D rows = n (B rows), cols = m -> acc[nf][mf]
        #pragma unroll
        for (int nf = 0; nf < 2; ++nf)
            #pragma unroll
            for (int mf = 0; mf < 4; ++mf)
                acc[nf][mf] = __builtin_amdgcn_mfma_f32_16x16x32_bf16(bv[nf], av[mf], acc[nf][mf], 0, 0, 0);
    }
}

static __device__ __forceinline__ void swz_block(int& bx, int& by) {
    int gx = gridDim.x;
    int nwg = gx * gridDim.y;
    int wg = by * gx + bx;
    int q = nwg >> 3;                    // nwg % 8 == 0 in all uses (bijective)
    wg = (wg & 7) * q + (wg >> 3);
    bx = wg % gx; by = wg / gx;
}

// ================= kernel 1: in_proj MFMA GEMM + split + softplus(dt) =================
__global__ __launch_bounds__(512) void k_gemm_in(
    const bf16* __restrict__ xb, const bf16* __restrict__ Wb,
    const float* __restrict__ dt_bias,
    bf16* __restrict__ z, bf16* __restrict__ xbc, float* __restrict__ dtb)
{
    __shared__ bf16 ldsA[3 * 4096];
    __shared__ bf16 ldsB[3 * 4096];
    int bx = blockIdx.x, by = blockIdx.y;
    swz_block(bx, by);
    const int m0 = by * 128, n0 = bx * 128;
    f32x4 acc[2][4] = {};
    gemm_core<DMODEL>(xb, Wb, m0, n0, ldsA, ldsB, acc);
    const int l = threadIdx.x & 63, w = threadIdx.x >> 6;
    const int wr = w >> 2, wc = w & 3, lq = l & 15, lk = l >> 4;
    const int mg = m0 + wr * 64, ng = n0 + wc * 32;
    if (n0 < DINNER) {                       // whole tile in z
        #pragma unroll
        for (int nf = 0; nf < 2; ++nf)
            #pragma unroll
            for (int mf = 0; mf < 4; ++mf) {
                int n = ng + nf * 16 + lk * 4;
                int m = mg + mf * 16 + lq;
                *(us4*)(z + (size_t)m * DINNER + n) = pack4(acc[nf][mf]);
            }
    } else if (n0 < DINNER + CONVDIM) {      // whole tile in xbc
        #pragma unroll
        for (int nf = 0; nf < 2; ++nf)
            #pragma unroll
            for (int mf = 0; mf < 4; ++mf) {
                int n = ng + nf * 16 + lk * 4 - DINNER;
                int m = mg + mf * 16 + lq;
                *(us4*)(xbc + (size_t)m * CONVDIM + n) = pack4(acc[nf][mf]);
            }
    } else {                                 // dt block (+ zero pad)
        #pragma unroll
        for (int nf = 0; nf < 2; ++nf)
            #pragma unroll
            for (int mf = 0; mf < 4; ++mf)
                #pragma unroll
                for (int j = 0; j < 4; ++j) {
                    int n = ng + nf * 16 + lk * 4 + j;
                    int m = mg + mf * 16 + lq;
                    if (n < DINPROJ) {
                        int h = n - (DINNER + CONVDIM);
                        float t = acc[nf][mf][j] + dt_bias[h];
                        dtb[(size_t)m * NHEADS + h] = (t > 20.f) ? t : log1pf(__expf(t));
                    }
                }
    }
}

// ================= kernel 8: out_proj MFMA GEMM + residual =================
__global__ __launch_bounds__(512) void k_gemm_out(
    const bf16* __restrict__ gb, const bf16* __restrict__ Wb,
    const float* __restrict__ xres, float* __restrict__ outp)
{
    __shared__ bf16 ldsA[3 * 4096];
    __shared__ bf16 ldsB[3 * 4096];
    int bx = blockIdx.x, by = blockIdx.y;
    swz_block(bx, by);
    const int m0 = by * 128, n0 = bx * 128;
    f32x4 acc[2][4] = {};
    gemm_core<DINNER>(gb, Wb, m0, n0, ldsA, ldsB, acc);
    const int l = threadIdx.x & 63, w = threadIdx.x >> 6;
    const int wr = w >> 2, wc = w & 3, lq = l & 15, lk = l >> 4;
    const int mg = m0 + wr * 64, ng = n0 + wc * 32;
    #pragma unroll
    for (int nf = 0; nf < 2; ++nf)
        #pragma unroll
        for (int mf = 0; mf < 4; ++mf) {
            int n = ng + nf * 16 + lk * 4;
            int m = mg + mf * 16 + lq;
            float4 r = *(const float4*)(xres + (size_t)m * DMODEL + n);
            float4 o = { r.x + acc[nf][mf][0], r.y + acc[nf][mf][1],
                         r.z + acc[nf][mf][2], r.w + acc[nf][mf][3] };
            *(float4*)(outp + (size_t)m * DMODEL + n) = o;
        }
}

// ================= kernel 2: causal depthwise conv(K=4) + SiLU + split =================
constexpr int CTOK = 8;
__global__ __launch_bounds__(320) void k_conv(
    const bf16* __restrict__ xbc, const float* __restrict__ cw, const float* __restrict__ cb,
    bf16* __restrict__ xs, bf16* __restrict__ Bm, bf16* __restrict__ Cm)
{
    const int m0 = blockIdx.x * CTOK;     // never crosses batch boundary (4096 % 8 == 0)
    const int c4 = threadIdx.x;           // [0,320)
    const int c = c4 * 4;
    const int l0 = m0 & 4095;
    float4 cbv = ((const float4*)cb)[c4];
    const float4 w0 = ((const float4*)cw)[c + 0];
    const float4 w1 = ((const float4*)cw)[c + 1];
    const float4 w2 = ((const float4*)cw)[c + 2];
    const float4 w3 = ((const float4*)cw)[c + 3];
    us4 rows[CTOK + 3];
    #pragma unroll
    for (int t = -3; t < CTOK; ++t) {
        int ll = l0 + t;
        if (ll >= 0) rows[t + 3] = *(const us4*)(xbc + (size_t)(m0 + t) * CONVDIM + c);
        else         rows[t + 3] = { 0, 0, 0, 0 };
    }
    #pragma unroll
    for (int t = 0; t < CTOK; ++t) {
        float a0 = cbv.x, a1 = cbv.y, a2 = cbv.z, a3 = cbv.w;
        #pragma unroll
        for (int k = 0; k < 4; ++k) {
            us4 v = rows[t + k];
            a0 += bfbits2f(v.a) * ((const float*)&w0)[k];
            a1 += bfbits2f(v.b) * ((const float*)&w1)[k];
            a2 += bfbits2f(v.c) * ((const float*)&w2)[k];
            a3 += bfbits2f(v.d) * ((const float*)&w3)[k];
        }
        us4 o = { f2bf_bits(a0 * sigmoidf_(a0)), f2bf_bits(a1 * sigmoidf_(a1)),
                  f2bf_bits(a2 * sigmoidf_(a2)), f2bf_bits(a3 * sigmoidf_(a3)) };
        int m = m0 + t;
        if (c < DINNER)               *(us4*)(xs + (size_t)m * DINNER + c) = o;
        else if (c < DINNER + DSTATE) *(us4*)(Bm + (size_t)m * DSTATE + (c - DINNER)) = o;
        else                          *(us4*)(Cm + (size_t)m * DSTATE + (c - DINNER - DSTATE)) = o;
    }
}

// ================= kernel 3: MFMA G = C · B^T per (b,chunk), vectorized stores =================
__global__ __launch_bounds__(64) void k_gmat(
    const bf16* __restrict__ Cm, const bf16* __restrict__ Bm, bf16* __restrict__ G)
{
    const int bc = blockIdx.z;
    const int q0 = blockIdx.x * 64, s0 = blockIdx.y * 64;
    const int row0 = bc * CHUNK;
    const int l = threadIdx.x;
    const int lq = l & 15, lk = l >> 4;
    f32x4 acc[4][4] = {};   // [fs][fq]
    #pragma unroll
    for (int kc = 0; kc < 4; ++kc) {
        bf16x8 av[4], bv[4];
        #pragma unroll
        for (int f = 0; f < 4; ++f) {
            av[f] = *(const bf16x8*)(Cm + (size_t)(row0 + q0 + f * 16 + lq) * DSTATE + kc * 32 + lk * 8);
            bv[f] = *(const bf16x8*)(Bm + (size_t)(row0 + s0 + f * 16 + lq) * DSTATE + kc * 32 + lk * 8);
        }
        #pragma unroll
        for (int fs = 0; fs < 4; ++fs)
            #pragma unroll
            for (int fq = 0; fq < 4; ++fq)
                acc[fs][fq] = __builtin_amdgcn_mfma_f32_16x16x32_bf16(bv[fs], av[fq], acc[fs][fq], 0, 0, 0);
    }
    #pragma unroll
    for (int fs = 0; fs < 4; ++fs)
        #pragma unroll
        for (int fq = 0; fq < 4; ++fq) {
            int q = q0 + fq * 16 + lq;
            int s = s0 + fs * 16 + lk * 4;
            *(us4*)(G + ((size_t)bc * CHUNK + q) * CHUNK + s) = pack4(acc[fs][fq]);
        }
}

// ================= kernel 4: MFMA SSD per (b,c,h): y = (L∘G)·X + D*xs ; states =================
__global__ __launch_bounds__(256) void k_ssd(
    const bf16* __restrict__ xs /* == y */, const bf16* __restrict__ Bm,
    const float* __restrict__ dtb, const float* __restrict__ A_log,
    const float* __restrict__ Dp, const bf16* __restrict__ G,
    bf16* __restrict__ y, bf16* __restrict__ states, float* __restrict__ asum)
{
    const int h = blockIdx.x, c = blockIdx.y, b = blockIdx.z;
    const int tid = threadIdx.x;
    const int l = tid & 63, w = tid >> 6;
    const int lq = l & 15, lk = l >> 4;
    __shared__ float sa[CHUNK], sdt[CHUNK], sdec[CHUNK];
    __shared__ __bf16 Xt[HEADDIM][136];   // [p][s] = xs*dt transposed
    __shared__ __bf16 Bt[DSTATE][136];    // [n][s] = B transposed
    const int row0 = b * SEQ + c * CHUNK;
    const int bc = b * NCHUNK + c;
    const float Ah = -__expf(A_log[h]);
    const float Dh = Dp[h];
    if (tid < CHUNK) {
        float d = dtb[(size_t)(row0 + tid) * NHEADS + h];
        sdt[tid] = d;
        sa[tid] = d * Ah;
    }
    __syncthreads();
    for (int off = 1; off < CHUNK; off <<= 1) {
        float v = 0.f;
        if (tid < CHUNK && tid >= off) v = sa[tid - off];
        __syncthreads();
        if (tid < CHUNK) sa[tid] += v;
        __syncthreads();
    }
    const float alast = sa[CHUNK - 1];
    if (tid < CHUNK) sdec[tid] = __expf(alast - sa[tid]);
    __syncthreads();
    {
        const int s = tid >> 1;
        const float dts = sdt[s];
        #pragma unroll
        for (int li = 0; li < 4; ++li) {
            int p0 = (tid & 1) * 8 + li * 16;
            bf16x8 v = *(const bf16x8*)(xs + (size_t)(row0 + s) * DINNER + h * HEADDIM + p0);
            #pragma unroll
            for (int i = 0; i < 8; ++i) Xt[p0 + i][s] = (__bf16)((float)v[i] * dts);
        }
        #pragma unroll
        for (int li = 0; li < 8; ++li) {
            int n0 = (tid & 1) * 8 + li * 16;
            bf16x8 v = *(const bf16x8*)(Bm + (size_t)(row0 + s) * DSTATE + n0);
            #pragma unroll
            for (int i = 0; i < 8; ++i) Bt[n0 + i][s] = v[i];
        }
    }
    __syncthreads();
    // ---- phase C: Y_diag = (L∘G)·X. mfma(X_frag_p, W_frag_q) -> D rows=p, cols=q
    __builtin_amdgcn_s_setprio(1);
    {
        const int q0 = w * 32;
        f32x4 acc[4][2] = {};   // [pf][fr]
        #pragma unroll
        for (int kc = 0; kc < 4; ++kc) {
            const int sbase = kc * 32 + lk * 8;
            bf16x8 av[2];
            #pragma unroll
            for (int fr = 0; fr < 2; ++fr) {
                int q = q0 + fr * 16 + lq;
                bf16x8 g = *(const bf16x8*)(G + ((size_t)bc * CHUNK + q) * CHUNK + sbase);
                float saq = sa[q];
                bf16x8 wv;
                #pragma unroll
                for (int j = 0; j < 8; ++j) {
                    int s = sbase + j;
                    float val = (s <= q) ? __expf(saq - sa[s]) * (float)g[j] : 0.f;
                    wv[j] = (__bf16)val;
                }
                av[fr] = wv;
            }
            #pragma unroll
            for (int pf = 0; pf < 4; ++pf) {
                bf16x8 xv = *(const bf16x8*)&Xt[pf * 16 + lq][sbase];
                #pragma unroll
                for (int fr = 0; fr < 2; ++fr)
                    acc[pf][fr] = __builtin_amdgcn_mfma_f32_16x16x32_bf16(xv, av[fr], acc[pf][fr], 0, 0, 0);
            }
        }
        #pragma unroll
        for (int fr = 0; fr < 2; ++fr)
            #pragma unroll
            for (int pf = 0; pf < 4; ++pf) {
                int q = q0 + fr * 16 + lq;
                int p = pf * 16 + lk * 4;
                size_t idx = (size_t)(row0 + q) * DINNER + h * HEADDIM + p;
                us4 xv4 = *(const us4*)(xs + idx);   // read original before write (y==xs alias)
                f32x4 a = acc[pf][fr];
                us4 o = { f2bf_bits(a[0] + Dh * bfbits2f(xv4.a)),
                          f2bf_bits(a[1] + Dh * bfbits2f(xv4.b)),
                          f2bf_bits(a[2] + Dh * bfbits2f(xv4.c)),
                          f2bf_bits(a[3] + Dh * bfbits2f(xv4.d)) };
                *(us4*)(y + idx) = o;
            }
    }
    // ---- phase D: states = (X*dec)·B^T. mfma(B_frag_n, Xdec_frag_p) -> D rows=n, cols=p
    {
        const int n0 = w * 32;
        f32x4 acc[2][4] = {};   // [nf][pf]
        #pragma unroll
        for (int kc = 0; kc < 4; ++kc) {
            const int sbase = kc * 32 + lk * 8;
            bf16x8 xd[4];
            #pragma unroll
            for (int pf = 0; pf < 4; ++pf) {
                bf16x8 xv = *(const bf16x8*)&Xt[pf * 16 + lq][sbase];
                bf16x8 sc;
                #pragma unroll
                for (int j = 0; j < 8; ++j) sc[j] = (__bf16)((float)xv[j] * sdec[sbase + j]);
                xd[pf] = sc;
            }
            #pragma unroll
            for (int nf = 0; nf < 2; ++nf) {
                bf16x8 bb = *(const bf16x8*)&Bt[n0 + nf * 16 + lq][sbase];
                #pragma unroll
                for (int pf = 0; pf < 4; ++pf)
                    acc[nf][pf] = __builtin_amdgcn_mfma_f32_16x16x32_bf16(bb, xd[pf], acc[nf][pf], 0, 0, 0);
            }
        }
        __builtin_amdgcn_s_setprio(0);
        const size_t sb = ((size_t)bc * NHEADS + h) * (HEADDIM * DSTATE);
        #pragma unroll
        for (int nf = 0; nf < 2; ++nf)
            #pragma unroll
            for (int pf = 0; pf < 4; ++pf) {
                int p = pf * 16 + lq;
                int n = n0 + nf * 16 + lk * 4;
                *(us4*)(states + sb + (size_t)p * DSTATE + n) = pack4(acc[nf][pf]);
            }
    }
    if (tid == 0) asum[bc * NHEADS + h] = alast;
}

// ================= kernel 5: inter-chunk sequential scan (16 segments) =================
__global__ __launch_bounds__(256) void k_scan(bf16* __restrict__ states, const float* __restrict__ asum)
{
    const int h = blockIdx.x, b = blockIdx.y, seg = blockIdx.z;
    const int e0 = seg * 512 + threadIdx.x;
    float P[2];
    P[0] = 0.f; P[1] = 0.f;
    for (int c = 0; c < NCHUNK; ++c) {
        size_t base = ((size_t)(b * NCHUNK + c) * NHEADS + h) * (HEADDIM * DSTATE);
        float dec = __expf(asum[(b * NCHUNK + c) * NHEADS + h]);
        #pragma unroll
        for (int j = 0; j < 2; ++j) {
            size_t e = base + e0 + j * 256;
            float sc = __bfloat162float(states[e]);
            states[e] = __float2bfloat16(P[j]);
            P[j] = dec * P[j] + sc;
        }
    }
}

// ================= kernel 6: MFMA y += exp(a_cs) * C · prev^T, vectorized RMW =================
__global__ __launch_bounds__(256) void k_yoff(
    const bf16* __restrict__ Cm,
    const float* __restrict__ dtb, const float* __restrict__ A_log,
    const bf16* __restrict__ states,
    bf16* __restrict__ y)
{
    const int h = blockIdx.x, c = blockIdx.y, b = blockIdx.z;
    const int tid = threadIdx.x;
    const int l = tid & 63, w = tid >> 6;
    const int lq = l & 15, lk = l >> 4;
    __shared__ float sa[CHUNK];
    const int row0 = b * SEQ + c * CHUNK;
    const int bc = b * NCHUNK + c;
    const float Ah = -__expf(A_log[h]);
    if (tid < CHUNK) {
        float d = dtb[(size_t)(row0 + tid) * NHEADS + h];
        sa[tid] = d * Ah;
    }
    __syncthreads();
    for (int off = 1; off < CHUNK; off <<= 1) {
        float v = 0.f;
        if (tid < CHUNK && tid >= off) v = sa[tid - off];
        __syncthreads();
        if (tid < CHUNK) sa[tid] += v;
        __syncthreads();
    }
    const size_t sb = ((size_t)bc * NHEADS + h) * (HEADDIM * DSTATE);
    const int q0 = w * 32;
    f32x4 acc[4][2] = {};   // [fc(p)][fr(q)]
    #pragma unroll
    for (int kc = 0; kc < 4; ++kc) {
        const int nbase = kc * 32 + lk * 8;
        bf16x8 av[2], bv[4];
        #pragma unroll
        for (int fr = 0; fr < 2; ++fr)
            av[fr] = *(const bf16x8*)(Cm + (size_t)(row0 + q0 + fr * 16 + lq) * DSTATE + nbase);
        #pragma unroll
        for (int fc = 0; fc < 4; ++fc)
            bv[fc] = *(const bf16x8*)(states + sb + (size_t)(fc * 16 + lq) * DSTATE + nbase);
        #pragma unroll
        for (int fc = 0; fc < 4; ++fc)
            #pragma unroll
            for (int fr = 0; fr < 2; ++fr)
                acc[fc][fr] = __builtin_amdgcn_mfma_f32_16x16x32_bf16(bv[fc], av[fr], acc[fc][fr], 0, 0, 0);
    }
    #pragma unroll
    for (int fr = 0; fr < 2; ++fr)
        #pragma unroll
        for (int fc = 0; fc < 4; ++fc) {
            int q = q0 + fr * 16 + lq;
            int p = fc * 16 + lk * 4;
            size_t idx = (size_t)(row0 + q) * DINNER + h * HEADDIM + p;
            const float eq = __expf(sa[q]);
            us4 cur = *(const us4*)(y + idx);
            f32x4 a = acc[fc][fr];
            us4 o = { f2bf_bits(bfbits2f(cur.a) + eq * a[0]),
                      f2bf_bits(bfbits2f(cur.b) + eq * a[1]),
                      f2bf_bits(bfbits2f(cur.c) + eq * a[2]),
                      f2bf_bits(bfbits2f(cur.d) + eq * a[3]) };
            *(us4*)(y + idx) = o;
        }
}

// ================= kernel 7: gated RMSNorm -> bf16 g (g aliases z; vectorized) =================
__global__ __launch_bounds__(256) void k_norm(
    const bf16* __restrict__ y, const bf16* __restrict__ z,
    const float* __restrict__ norm_w, bf16* __restrict__ g)
{
    const int tid = threadIdx.x;
    const int tk = tid >> 7;             // token within block
    const int lane = tid & 127;
    const int m = blockIdx.x * 2 + tk;
    const int e0 = lane * 8;
    bf16x8 z8 = *(const bf16x8*)(z + (size_t)m * DINNER + e0);
    bf16x8 y8 = *(const bf16x8*)(y + (size_t)m * DINNER + e0);
    float gg[8];
    float ss = 0.f;
    #pragma unroll
    for (int i = 0; i < 8; ++i) {
        float zz = (float)z8[i];
        gg[i] = (float)y8[i] * (zz * sigmoidf_(zz));
        ss += gg[i] * gg[i];
    }
    #pragma unroll
    for (int o = 32; o > 0; o >>= 1) ss += __shfl_xor(ss, o, 64);
    __shared__ float red[4];
    if ((tid & 63) == 0) red[tid >> 6] = ss;
    __syncthreads();
    const float scale = rsqrtf((red[tk * 2] + red[tk * 2 + 1]) / DINNER + 1e-5f);
    const float4 nw0 = *(const float4*)(norm_w + e0);
    const float4 nw1 = *(const float4*)(norm_w + e0 + 4);
    bf16x8 o8;
    o8[0] = (__bf16)(gg[0] * scale * nw0.x);
    o8[1] = (__bf16)(gg[1] * scale * nw0.y);
    o8[2] = (__bf16)(gg[2] * scale * nw0.z);
    o8[3] = (__bf16)(gg[3] * scale * nw0.w);
    o8[4] = (__bf16)(gg[4] * scale * nw1.x);
    o8[5] = (__bf16)(gg[5] * scale * nw1.y);
    o8[6] = (__bf16)(gg[6] * scale * nw1.z);
    o8[7] = (__bf16)(gg[7] * scale * nw1.w);
    *(bf16x8*)(g + (size_t)m * DINNER + e0) = o8;
}

// ================= launch =================
extern "C" void kernel_launch(void* const* d_in, const int* in_sizes, int n_in,
                              void* d_out, int out_size, void* d_ws, size_t ws_size,
                              hipStream_t stream) {
    const float* x       = (const float*)d_in[0];
    const float* W_in    = (const float*)d_in[1];
    const float* conv_w  = (const float*)d_in[2];
    const float* conv_b  = (const float*)d_in[3];
    const float* dt_bias = (const float*)d_in[4];
    const float* A_log   = (const float*)d_in[5];
    const float* Dp      = (const float*)d_in[6];
    const float* norm_w  = (const float*)d_in[7];
    const float* W_out   = (const float*)d_in[8];
    float* out = (float*)d_out;

    if (ws_size < WS_NEED) {
        k_sentinel<<<1, 1, 0, stream>>>(out);
        return;
    }

    char* ws = (char*)d_ws;
    bf16* z     = (bf16*)(ws + OFF_Z);
    bf16* gb    = (bf16*)(ws + OFF_Z);    // g aliases z
    bf16* xbc   = (bf16*)(ws + OFF_XBC);
    bf16* st    = (bf16*)(ws + OFF_XBC);  // states alias xbc
    float* dtb  = (float*)(ws + OFF_DT);
    bf16* xs    = (bf16*)(ws + OFF_XS);
    bf16* yb    = (bf16*)(ws + OFF_XS);   // y aliases xs
    bf16* xb    = (bf16*)(ws + OFF_XS);   // bf16 x, dead before k_conv writes xs
    bf16* Bm    = (bf16*)(ws + OFF_B);
    bf16* Wbin  = (bf16*)(ws + OFF_B);    // bf16 W_in (padded), dead before k_conv writes Bm
    bf16* Cm    = (bf16*)(ws + OFF_C);
    bf16* G     = (bf16*)(ws + OFF_G);
    bf16* Wbout = (bf16*)(ws + OFF_G);    // bf16 W_out, cast after k_ssd consumed G
    float* asum = (float*)(ws + OFF_ASUM);

    k_cast_x<<<(MTOT * DMODEL / 4 + 255) / 256, 256, 0, stream>>>(x, xb, MTOT * DMODEL / 4);
    k_cast_win<<<(NPAD * DMODEL / 4 + 255) / 256, 256, 0, stream>>>(W_in, Wbin);
    k_gemm_in<<<dim3(NPAD / 128, MTOT / 128), 512, 0, stream>>>(xb, Wbin, dt_bias, z, xbc, dtb);
    k_conv<<<MTOT / CTOK, 320, 0, stream>>>(xbc, conv_w, conv_b, xs, Bm, Cm);
    k_gmat<<<dim3(2, 2, BSZ * NCHUNK), 64, 0, stream>>>(Cm, Bm, G);
    k_ssd<<<dim3(NHEADS, NCHUNK, BSZ), 256, 0, stream>>>(xs, Bm, dtb, A_log, Dp, G, yb, st, asum);
    k_cast_x<<<(DMODEL * DINNER / 4 + 255) / 256, 256, 0, stream>>>(W_out, Wbout, DMODEL * DINNER / 4);
    k_scan<<<dim3(NHEADS, BSZ, 16), 256, 0, stream>>>(st, asum);
    k_yoff<<<dim3(NHEADS, NCHUNK, BSZ), 256, 0, stream>>>(Cm, dtb, A_log, st, yb);
    k_norm<<<MTOT / 2, 256, 0, stream>>>(yb, z, norm_w, gb);
    k_gemm_out<<<dim3(DMODEL / 128, MTOT / 128), 512, 0, stream>>>(gb, Wbout, x, out);
}

// Round 16
// 258.775 us; speedup vs baseline: 1.0377x; 1.0055x over previous
//
#include <hip/hip_runtime.h>
#include <hip/hip_bf16.h>

typedef __hip_bfloat16 bf16;
typedef __attribute__((ext_vector_type(8))) __bf16 bf16x8;
typedef __attribute__((ext_vector_type(4))) float f32x4;

// ---------------- problem constants ----------------
constexpr int BSZ = 4, SEQ = 4096, DMODEL = 512;
constexpr int DSTATE = 128, HEADDIM = 64, DINNER = 1024, NHEADS = 16, CHUNK = 128;
constexpr int CONVDIM = DINNER + 2 * DSTATE;              // 1280
constexpr int DINPROJ = 2 * DINNER + 2 * DSTATE + NHEADS; // 2320
constexpr int NPAD = 2432;                                // 19*128, padded N for in_proj
constexpr int MTOT = BSZ * SEQ;                           // 16384
constexpr int NCHUNK = SEQ / CHUNK;                       // 32

// ---------------- workspace layout (bytes) ----------------
constexpr size_t OFF_Z    = 0;                                               // bf16 [MTOT][DINNER]
constexpr size_t OFF_XBC  = OFF_Z    + (size_t)MTOT * DINNER * 2;            // bf16 [MTOT][CONVDIM]
constexpr size_t OFF_DT   = OFF_XBC  + (size_t)MTOT * CONVDIM * 2;           // f32  [MTOT][NHEADS]
constexpr size_t OFF_XS   = OFF_DT   + (size_t)MTOT * NHEADS * 4;            // bf16 [MTOT][DINNER]
constexpr size_t OFF_B    = OFF_XS   + (size_t)MTOT * DINNER * 2;            // bf16 [MTOT][DSTATE]
constexpr size_t OFF_C    = OFF_B    + (size_t)MTOT * DSTATE * 2;            // bf16 [MTOT][DSTATE]
constexpr size_t OFF_G    = OFF_C    + (size_t)MTOT * DSTATE * 2;            // bf16 [B*NC][128][128]
constexpr size_t OFF_ASUM = OFF_G    + (size_t)BSZ * NCHUNK * CHUNK * CHUNK * 2; // f32
constexpr size_t WS_NEED  = OFF_ASUM + 8192;                                 // ~117MiB

static __device__ __forceinline__ float sigmoidf_(float x) { return 1.f / (1.f + __expf(-x)); }
static __device__ __forceinline__ unsigned short f2bf_bits(float f) {
    __hip_bfloat16 h = __float2bfloat16(f);
    return *reinterpret_cast<unsigned short*>(&h);
}
static __device__ __forceinline__ float bfbits2f(unsigned short u) {
    return __bfloat162float(*reinterpret_cast<bf16*>(&u));
}
struct us4 { unsigned short a, b, c, d; };
static __device__ __forceinline__ us4 pack4(const f32x4 v) {
    return { f2bf_bits(v[0]), f2bf_bits(v[1]), f2bf_bits(v[2]), f2bf_bits(v[3]) };
}

__global__ void k_sentinel(float* out) { out[0] = 1.0e9f; }

// ================= cast kernels =================
__global__ __launch_bounds__(256) void k_cast_x(const float* __restrict__ in, bf16* __restrict__ out, int n4) {
    int i = blockIdx.x * 256 + threadIdx.x;
    if (i >= n4) return;
    float4 f = ((const float4*)in)[i];
    us4 v = { f2bf_bits(f.x), f2bf_bits(f.y), f2bf_bits(f.z), f2bf_bits(f.w) };
    ((us4*)out)[i] = v;
}

__global__ __launch_bounds__(256) void k_cast_win(const float* __restrict__ W, bf16* __restrict__ out) {
    int i = blockIdx.x * 256 + threadIdx.x;
    if (i >= NPAD * (DMODEL / 4)) return;
    int row = i / (DMODEL / 4);
    us4 v;
    if (row < DINPROJ) {
        float4 f = ((const float4*)W)[i];
        v = { f2bf_bits(f.x), f2bf_bits(f.y), f2bf_bits(f.z), f2bf_bits(f.w) };
    } else {
        v = { 0, 0, 0, 0 };
    }
    ((us4*)out)[i] = v;
}

// ================= MFMA GEMM core: 8-wave variant of the R5 proven pipeline =================
// Same 128x128 tile, 3-buf BK=32, both operands via inverse-swizzled global_load_lds,
// counted vmcnt gate. 512 threads = 8 waves (2M x 4N), per-wave output 64x32.
// LDS per buffer: 64 rows x 128B; logical chunk L = phys ^ (row&7);
// tile row = (L>>2)*64 + row; k-chunk = L&3.
// Stage: ONE gload per thread per operand; wave w covers LDS rows w*8..w*8+8
// (dest = wave-uniform base + lane*16B). Gate: vmcnt(2) (next stage's 2 loads in flight).
typedef const __attribute__((address_space(1))) void* gas_t;
typedef __attribute__((address_space(3))) void* las_t;
static __device__ __forceinline__ void gload_lds16(const void* g, void* l) {
    __builtin_amdgcn_global_load_lds((gas_t)g, (las_t)l, 16, 0, 0);
}

template<int K>
static __device__ __forceinline__ void gemm_core(
    const bf16* __restrict__ A, const bf16* __restrict__ B,
    int m0, int n0, bf16* ldsA, bf16* ldsB, f32x4 acc[2][4])
{
    constexpr int NT = K / 32;
    const int tid = threadIdx.x;           // [0,512)
    const int l = tid & 63, w = tid >> 6;  // 8 waves
    const int wr = w >> 2, wc = w & 3;     // 2M x 4N
    const int lq = l & 15, lk = l >> 4;

    auto stage = [&](int buf, int t) {
        const int k0 = t * 32;
        const int q = w * 8 + (l >> 3);      // LDS row [0,64)
        const int p = l & 7;                 // phys 16B chunk
        const int L = p ^ (q & 7);           // logical chunk
        const int ra = (L >> 2) * 64 + q;    // tile row [0,128)
        const int ck = L & 3;                // k-chunk (8 bf16)
        gload_lds16(A + (size_t)(m0 + ra) * K + k0 + ck * 8,
                    ldsA + buf * 4096 + w * 512);   // wave-uniform base + lane*16B
        gload_lds16(B + (size_t)(n0 + ra) * K + k0 + ck * 8,
                    ldsB + buf * 4096 + w * 512);
    };

    stage(0, 0);
    stage(1, 1);
    for (int t = 0; t < NT; ++t) {
        if (t + 1 < NT) asm volatile("s_waitcnt vmcnt(2)" ::: "memory");
        else            asm volatile("s_waitcnt vmcnt(0)" ::: "memory");
        __builtin_amdgcn_s_barrier();
        __builtin_amdgcn_sched_barrier(0);
        if (t + 2 < NT) stage((t + 2) % 3, t + 2);
        const int buf = t % 3;
        bf16x8 av[4], bv[2];
        #pragma unroll
        for (int f = 0; f < 4; ++f) {
            int ra = wr * 64 + f * 16 + lq;
            int qa = ra & 63, La = (ra >> 6) * 4 + lk, pa = La ^ (qa & 7);
            av[f] = *(const bf16x8*)(ldsA + buf * 4096 + qa * 64 + pa * 8);
        }
        #pragma unroll
        for (int f = 0; f < 2; ++f) {
            int rb = wc * 32 + f * 16 + lq;
            int qb = rb & 63, Lb = (rb >> 6) * 4 + lk, pb = Lb ^ (qb & 7);
            bv[f] = *(const bf16x8*)(ldsB + buf * 4096 + qb * 64 + pb * 8);
        }
        // swapped operands: D rows = n (B rows), cols = m -> acc[nf][mf]
        #pragma unroll
        for (int nf = 0; nf < 2; ++nf)
            #pragma unroll
            for (int mf = 0; mf < 4; ++mf)
                acc[nf][mf] = __builtin_amdgcn_mfma_f32_16x16x32_bf16(bv[nf], av[mf], acc[nf][mf], 0, 0, 0);
    }
}

static __device__ __forceinline__ void swz_block(int& bx, int& by) {
    int gx = gridDim.x;
    int nwg = gx * gridDim.y;
    int wg = by * gx + bx;
    int q = nwg >> 3;                    // nwg % 8 == 0 in all uses (bijective)
    wg = (wg & 7) * q + (wg >> 3);
    bx = wg % gx; by = wg / gx;
}

// ================= kernel 1: in_proj MFMA GEMM + split + softplus(dt) =================
__global__ __launch_bounds__(512) void k_gemm_in(
    const bf16* __restrict__ xb, const bf16* __restrict__ Wb,
    const float* __restrict__ dt_bias,
    bf16* __restrict__ z, bf16* __restrict__ xbc, float* __restrict__ dtb)
{
    __shared__ bf16 ldsA[3 * 4096];
    __shared__ bf16 ldsB[3 * 4096];
    int bx = blockIdx.x, by = blockIdx.y;
    swz_block(bx, by);
    const int m0 = by * 128, n0 = bx * 128;
    f32x4 acc[2][4] = {};
    gemm_core<DMODEL>(xb, Wb, m0, n0, ldsA, ldsB, acc);
    const int l = threadIdx.x & 63, w = threadIdx.x >> 6;
    const int wr = w >> 2, wc = w & 3, lq = l & 15, lk = l >> 4;
    const int mg = m0 + wr * 64, ng = n0 + wc * 32;
    if (n0 < DINNER) {                       // whole tile in z
        #pragma unroll
        for (int nf = 0; nf < 2; ++nf)
            #pragma unroll
            for (int mf = 0; mf < 4; ++mf) {
                int n = ng + nf * 16 + lk * 4;
                int m = mg + mf * 16 + lq;
                *(us4*)(z + (size_t)m * DINNER + n) = pack4(acc[nf][mf]);
            }
    } else if (n0 < DINNER + CONVDIM) {      // whole tile in xbc
        #pragma unroll
        for (int nf = 0; nf < 2; ++nf)
            #pragma unroll
            for (int mf = 0; mf < 4; ++mf) {
                int n = ng + nf * 16 + lk * 4 - DINNER;
                int m = mg + mf * 16 + lq;
                *(us4*)(xbc + (size_t)m * CONVDIM + n) = pack4(acc[nf][mf]);
            }
    } else {                                 // dt block (+ zero pad)
        #pragma unroll
        for (int nf = 0; nf < 2; ++nf)
            #pragma unroll
            for (int mf = 0; mf < 4; ++mf)
                #pragma unroll
                for (int j = 0; j < 4; ++j) {
                    int n = ng + nf * 16 + lk * 4 + j;
                    int m = mg + mf * 16 + lq;
                    if (n < DINPROJ) {
                        int h = n - (DINNER + CONVDIM);
                        float t = acc[nf][mf][j] + dt_bias[h];
                        dtb[(size_t)m * NHEADS + h] = (t > 20.f) ? t : log1pf(__expf(t));
                    }
                }
    }
}

// ================= kernel 8: out_proj MFMA GEMM + residual =================
__global__ __launch_bounds__(512) void k_gemm_out(
    const bf16* __restrict__ gb, const bf16* __restrict__ Wb,
    const float* __restrict__ xres, float* __restrict__ outp)
{
    __shared__ bf16 ldsA[3 * 4096];
    __shared__ bf16 ldsB[3 * 4096];
    int bx = blockIdx.x, by = blockIdx.y;
    swz_block(bx, by);
    const int m0 = by * 128, n0 = bx * 128;
    f32x4 acc[2][4] = {};
    gemm_core<DINNER>(gb, Wb, m0, n0, ldsA, ldsB, acc);
    const int l = threadIdx.x & 63, w = threadIdx.x >> 6;
    const int wr = w >> 2, wc = w & 3, lq = l & 15, lk = l >> 4;
    const int mg = m0 + wr * 64, ng = n0 + wc * 32;
    #pragma unroll
    for (int nf = 0; nf < 2; ++nf)
        #pragma unroll
        for (int mf = 0; mf < 4; ++mf) {
            int n = ng + nf * 16 + lk * 4;
            int m = mg + mf * 16 + lq;
            float4 r = *(const float4*)(xres + (size_t)m * DMODEL + n);
            float4 o = { r.x + acc[nf][mf][0], r.y + acc[nf][mf][1],
                         r.z + acc[nf][mf][2], r.w + acc[nf][mf][3] };
            *(float4*)(outp + (size_t)m * DMODEL + n) = o;
        }
}

// ================= kernel 2: causal depthwise conv(K=4) + SiLU + split =================
constexpr int CTOK = 8;
__global__ __launch_bounds__(320) void k_conv(
    const bf16* __restrict__ xbc, const float* __restrict__ cw, const float* __restrict__ cb,
    bf16* __restrict__ xs, bf16* __restrict__ Bm, bf16* __restrict__ Cm)
{
    const int m0 = blockIdx.x * CTOK;     // never crosses batch boundary (4096 % 8 == 0)
    const int c4 = threadIdx.x;           // [0,320)
    const int c = c4 * 4;
    const int l0 = m0 & 4095;
    float4 cbv = ((const float4*)cb)[c4];
    const float4 w0 = ((const float4*)cw)[c + 0];
    const float4 w1 = ((const float4*)cw)[c + 1];
    const float4 w2 = ((const float4*)cw)[c + 2];
    const float4 w3 = ((const float4*)cw)[c + 3];
    us4 rows[CTOK + 3];
    #pragma unroll
    for (int t = -3; t < CTOK; ++t) {
        int ll = l0 + t;
        if (ll >= 0) rows[t + 3] = *(const us4*)(xbc + (size_t)(m0 + t) * CONVDIM + c);
        else         rows[t + 3] = { 0, 0, 0, 0 };
    }
    #pragma unroll
    for (int t = 0; t < CTOK; ++t) {
        float a0 = cbv.x, a1 = cbv.y, a2 = cbv.z, a3 = cbv.w;
        #pragma unroll
        for (int k = 0; k < 4; ++k) {
            us4 v = rows[t + k];
            a0 += bfbits2f(v.a) * ((const float*)&w0)[k];
            a1 += bfbits2f(v.b) * ((const float*)&w1)[k];
            a2 += bfbits2f(v.c) * ((const float*)&w2)[k];
            a3 += bfbits2f(v.d) * ((const float*)&w3)[k];
        }
        us4 o = { f2bf_bits(a0 * sigmoidf_(a0)), f2bf_bits(a1 * sigmoidf_(a1)),
                  f2bf_bits(a2 * sigmoidf_(a2)), f2bf_bits(a3 * sigmoidf_(a3)) };
        int m = m0 + t;
        if (c < DINNER)               *(us4*)(xs + (size_t)m * DINNER + c) = o;
        else if (c < DINNER + DSTATE) *(us4*)(Bm + (size_t)m * DSTATE + (c - DINNER)) = o;
        else                          *(us4*)(Cm + (size_t)m * DSTATE + (c - DINNER - DSTATE)) = o;
    }
}

// ================= kernel 3: MFMA G = C · B^T per (b,chunk), vectorized stores =================
__global__ __launch_bounds__(64) void k_gmat(
    const bf16* __restrict__ Cm, const bf16* __restrict__ Bm, bf16* __restrict__ G)
{
    const int bc = blockIdx.z;
    const int q0 = blockIdx.x * 64, s0 = blockIdx.y * 64;
    const int row0 = bc * CHUNK;
    const int l = threadIdx.x;
    const int lq = l & 15, lk = l >> 4;
    f32x4 acc[4][4] = {};   // [fs][fq]
    #pragma unroll
    for (int kc = 0; kc < 4; ++kc) {
        bf16x8 av[4], bv[4];
        #pragma unroll
        for (int f = 0; f < 4; ++f) {
            av[f] = *(const bf16x8*)(Cm + (size_t)(row0 + q0 + f * 16 + lq) * DSTATE + kc * 32 + lk * 8);
            bv[f] = *(const bf16x8*)(Bm + (size_t)(row0 + s0 + f * 16 + lq) * DSTATE + kc * 32 + lk * 8);
        }
        #pragma unroll
        for (int fs = 0; fs < 4; ++fs)
            #pragma unroll
            for (int fq = 0; fq < 4; ++fq)
                acc[fs][fq] = __builtin_amdgcn_mfma_f32_16x16x32_bf16(bv[fs], av[fq], acc[fs][fq], 0, 0, 0);
    }
    #pragma unroll
    for (int fs = 0; fs < 4; ++fs)
        #pragma unroll
        for (int fq = 0; fq < 4; ++fq) {
            int q = q0 + fq * 16 + lq;
            int s = s0 + fs * 16 + lk * 4;
            *(us4*)(G + ((size_t)bc * CHUNK + q) * CHUNK + s) = pack4(acc[fs][fq]);
        }
}

// ================= kernel 4: MFMA SSD per (b,c,h): y = (L∘G)·X + D*xs ; states =================
__global__ __launch_bounds__(256) void k_ssd(
    const bf16* __restrict__ xs /* == y */, const bf16* __restrict__ Bm,
    const float* __restrict__ dtb, const float* __restrict__ A_log,
    const float* __restrict__ Dp, const bf16* __restrict__ G,
    bf16* __restrict__ y, bf16* __restrict__ states, float* __restrict__ asum)
{
    const int h = blockIdx.x, c = blockIdx.y, b = blockIdx.z;
    const int tid = threadIdx.x;
    const int l = tid & 63, w = tid >> 6;
    const int lq = l & 15, lk = l >> 4;
    __shared__ float sa[CHUNK], sdt[CHUNK], sdec[CHUNK];
    __shared__ __bf16 Xt[HEADDIM][136];   // [p][s] = xs*dt transposed
    __shared__ __bf16 Bt[DSTATE][136];    // [n][s] = B transposed
    const int row0 = b * SEQ + c * CHUNK;
    const int bc = b * NCHUNK + c;
    const float Ah = -__expf(A_log[h]);
    const float Dh = Dp[h];
    if (tid < CHUNK) {
        float d = dtb[(size_t)(row0 + tid) * NHEADS + h];
        sdt[tid] = d;
        sa[tid] = d * Ah;
    }
    __syncthreads();
    for (int off = 1; off < CHUNK; off <<= 1) {
        float v = 0.f;
        if (tid < CHUNK && tid >= off) v = sa[tid - off];
        __syncthreads();
        if (tid < CHUNK) sa[tid] += v;
        __syncthreads();
    }
    const float alast = sa[CHUNK - 1];
    if (tid < CHUNK) sdec[tid] = __expf(alast - sa[tid]);
    __syncthreads();
    {
        const int s = tid >> 1;
        const float dts = sdt[s];
        #pragma unroll
        for (int li = 0; li < 4; ++li) {
            int p0 = (tid & 1) * 8 + li * 16;
            bf16x8 v = *(const bf16x8*)(xs + (size_t)(row0 + s) * DINNER + h * HEADDIM + p0);
            #pragma unroll
            for (int i = 0; i < 8; ++i) Xt[p0 + i][s] = (__bf16)((float)v[i] * dts);
        }
        #pragma unroll
        for (int li = 0; li < 8; ++li) {
            int n0 = (tid & 1) * 8 + li * 16;
            bf16x8 v = *(const bf16x8*)(Bm + (size_t)(row0 + s) * DSTATE + n0);
            #pragma unroll
            for (int i = 0; i < 8; ++i) Bt[n0 + i][s] = v[i];
        }
    }
    __syncthreads();
    // ---- phase C: Y_diag = (L∘G)·X. mfma(X_frag_p, W_frag_q) -> D rows=p, cols=q
    __builtin_amdgcn_s_setprio(1);
    {
        const int q0 = w * 32;
        f32x4 acc[4][2] = {};   // [pf][fr]
        #pragma unroll
        for (int kc = 0; kc < 4; ++kc) {
            const int sbase = kc * 32 + lk * 8;
            bf16x8 av[2];
            #pragma unroll
            for (int fr = 0; fr < 2; ++fr) {
                int q = q0 + fr * 16 + lq;
                bf16x8 g = *(const bf16x8*)(G + ((size_t)bc * CHUNK + q) * CHUNK + sbase);
                float saq = sa[q];
                bf16x8 wv;
                #pragma unroll
                for (int j = 0; j < 8; ++j) {
                    int s = sbase + j;
                    float val = (s <= q) ? __expf(saq - sa[s]) * (float)g[j] : 0.f;
                    wv[j] = (__bf16)val;
                }
                av[fr] = wv;
            }
            #pragma unroll
            for (int pf = 0; pf < 4; ++pf) {
                bf16x8 xv = *(const bf16x8*)&Xt[pf * 16 + lq][sbase];
                #pragma unroll
                for (int fr = 0; fr < 2; ++fr)
                    acc[pf][fr] = __builtin_amdgcn_mfma_f32_16x16x32_bf16(xv, av[fr], acc[pf][fr], 0, 0, 0);
            }
        }
        #pragma unroll
        for (int fr = 0; fr < 2; ++fr)
            #pragma unroll
            for (int pf = 0; pf < 4; ++pf) {
                int q = q0 + fr * 16 + lq;
                int p = pf * 16 + lk * 4;
                size_t idx = (size_t)(row0 + q) * DINNER + h * HEADDIM + p;
                us4 xv4 = *(const us4*)(xs + idx);   // read original before write (y==xs alias)
                f32x4 a = acc[pf][fr];
                us4 o = { f2bf_bits(a[0] + Dh * bfbits2f(xv4.a)),
                          f2bf_bits(a[1] + Dh * bfbits2f(xv4.b)),
                          f2bf_bits(a[2] + Dh * bfbits2f(xv4.c)),
                          f2bf_bits(a[3] + Dh * bfbits2f(xv4.d)) };
                *(us4*)(y + idx) = o;
            }
    }
    // ---- phase D: states = (X*dec)·B^T. mfma(B_frag_n, Xdec_frag_p) -> D rows=n, cols=p
    {
        const int n0 = w * 32;
        f32x4 acc[2][4] = {};   // [nf][pf]
        #pragma unroll
        for (int kc = 0; kc < 4; ++kc) {
            const int sbase = kc * 32 + lk * 8;
            bf16x8 xd[4];
            #pragma unroll
            for (int pf = 0; pf < 4; ++pf) {
                bf16x8 xv = *(const bf16x8*)&Xt[pf * 16 + lq][sbase];
                bf16x8 sc;
                #pragma unroll
                for (int j = 0; j < 8; ++j) sc[j] = (__bf16)((float)xv[j] * sdec[sbase + j]);
                xd[pf] = sc;
            }
            #pragma unroll
            for (int nf = 0; nf < 2; ++nf) {
                bf16x8 bb = *(const bf16x8*)&Bt[n0 + nf * 16 + lq][sbase];
                #pragma unroll
                for (int pf = 0; pf < 4; ++pf)
                    acc[nf][pf] = __builtin_amdgcn_mfma_f32_16x16x32_bf16(bb, xd[pf], acc[nf][pf], 0, 0, 0);
            }
        }
        __builtin_amdgcn_s_setprio(0);
        const size_t sb = ((size_t)bc * NHEADS + h) * (HEADDIM * DSTATE);
        #pragma unroll
        for (int nf = 0; nf < 2; ++nf)
            #pragma unroll
            for (int pf = 0; pf < 4; ++pf) {
                int p = pf * 16 + lq;
                int n = n0 + nf * 16 + lk * 4;
                *(us4*)(states + sb + (size_t)p * DSTATE + n) = pack4(acc[nf][pf]);
            }
    }
    if (tid == 0) asum[bc * NHEADS + h] = alast;
}

// ================= kernel 5: inter-chunk sequential scan (16 segments) =================
__global__ __launch_bounds__(256) void k_scan(bf16* __restrict__ states, const float* __restrict__ asum)
{
    const int h = blockIdx.x, b = blockIdx.y, seg = blockIdx.z;
    const int e0 = seg * 512 + threadIdx.x;
    float P[2];
    P[0] = 0.f; P[1] = 0.f;
    for (int c = 0; c < NCHUNK; ++c) {
        size_t base = ((size_t)(b * NCHUNK + c) * NHEADS + h) * (HEADDIM * DSTATE);
        float dec = __expf(asum[(b * NCHUNK + c) * NHEADS + h]);
        #pragma unroll
        for (int j = 0; j < 2; ++j) {
            size_t e = base + e0 + j * 256;
            float sc = __bfloat162float(states[e]);
            states[e] = __float2bfloat16(P[j]);
            P[j] = dec * P[j] + sc;
        }
    }
}

// ================= kernel 6: MFMA y += exp(a_cs) * C · prev^T, vectorized RMW =================
__global__ __launch_bounds__(256) void k_yoff(
    const bf16* __restrict__ Cm,
    const float* __restrict__ dtb, const float* __restrict__ A_log,
    const bf16* __restrict__ states,
    bf16* __restrict__ y)
{
    const int h = blockIdx.x, c = blockIdx.y, b = blockIdx.z;
    const int tid = threadIdx.x;
    const int l = tid & 63, w = tid >> 6;
    const int lq = l & 15, lk = l >> 4;
    __shared__ float sa[CHUNK];
    const int row0 = b * SEQ + c * CHUNK;
    const int bc = b * NCHUNK + c;
    const float Ah = -__expf(A_log[h]);
    if (tid < CHUNK) {
        float d = dtb[(size_t)(row0 + tid) * NHEADS + h];
        sa[tid] = d * Ah;
    }
    __syncthreads();
    for (int off = 1; off < CHUNK; off <<= 1) {
        float v = 0.f;
        if (tid < CHUNK && tid >= off) v = sa[tid - off];
        __syncthreads();
        if (tid < CHUNK) sa[tid] += v;
        __syncthreads();
    }
    const size_t sb = ((size_t)bc * NHEADS + h) * (HEADDIM * DSTATE);
    const int q0 = w * 32;
    f32x4 acc[4][2] = {};   // [fc(p)][fr(q)]
    #pragma unroll
    for (int kc = 0; kc < 4; ++kc) {
        const int nbase = kc * 32 + lk * 8;
        bf16x8 av[2], bv[4];
        #pragma unroll
        for (int fr = 0; fr < 2; ++fr)
            av[fr] = *(const bf16x8*)(Cm + (size_t)(row0 + q0 + fr * 16 + lq) * DSTATE + nbase);
        #pragma unroll
        for (int fc = 0; fc < 4; ++fc)
            bv[fc] = *(const bf16x8*)(states + sb + (size_t)(fc * 16 + lq) * DSTATE + nbase);
        #pragma unroll
        for (int fc = 0; fc < 4; ++fc)
            #pragma unroll
            for (int fr = 0; fr < 2; ++fr)
                acc[fc][fr] = __builtin_amdgcn_mfma_f32_16x16x32_bf16(bv[fc], av[fr], acc[fc][fr], 0, 0, 0);
    }
    #pragma unroll
    for (int fr = 0; fr < 2; ++fr)
        #pragma unroll
        for (int fc = 0; fc < 4; ++fc) {
            int q = q0 + fr * 16 + lq;
            int p = fc * 16 + lk * 4;
            size_t idx = (size_t)(row0 + q) * DINNER + h * HEADDIM + p;
            const float eq = __expf(sa[q]);
            us4 cur = *(const us4*)(y + idx);
            f32x4 a = acc[fc][fr];
            us4 o = { f2bf_bits(bfbits2f(cur.a) + eq * a[0]),
                      f2bf_bits(bfbits2f(cur.b) + eq * a[1]),
                      f2bf_bits(bfbits2f(cur.c) + eq * a[2]),
                      f2bf_bits(bfbits2f(cur.d) + eq * a[3]) };
            *(us4*)(y + idx) = o;
        }
}

// ================= kernel 7: gated RMSNorm -> bf16 g (g aliases z; vectorized) =================
__global__ __launch_bounds__(256) void k_norm(
    const bf16* __restrict__ y, const bf16* __restrict__ z,
    const float* __restrict__ norm_w, bf16* __restrict__ g)
{
    const int tid = threadIdx.x;
    const int tk = tid >> 7;             // token within block
    const int lane = tid & 127;
    const int m = blockIdx.x * 2 + tk;
    const int e0 = lane * 8;
    bf16x8 z8 = *(const bf16x8*)(z + (size_t)m * DINNER + e0);
    bf16x8 y8 = *(const bf16x8*)(y + (size_t)m * DINNER + e0);
    float gg[8];
    float ss = 0.f;
    #pragma unroll
    for (int i = 0; i < 8; ++i) {
        float zz = (float)z8[i];
        gg[i] = (float)y8[i] * (zz * sigmoidf_(zz));
        ss += gg[i] * gg[i];
    }
    #pragma unroll
    for (int o = 32; o > 0; o >>= 1) ss += __shfl_xor(ss, o, 64);
    __shared__ float red[4];
    if ((tid & 63) == 0) red[tid >> 6] = ss;
    __syncthreads();
    const float scale = rsqrtf((red[tk * 2] + red[tk * 2 + 1]) / DINNER + 1e-5f);
    const float4 nw0 = *(const float4*)(norm_w + e0);
    const float4 nw1 = *(const float4*)(norm_w + e0 + 4);
    bf16x8 o8;
    o8[0] = (__bf16)(gg[0] * scale * nw0.x);
    o8[1] = (__bf16)(gg[1] * scale * nw0.y);
    o8[2] = (__bf16)(gg[2] * scale * nw0.z);
    o8[3] = (__bf16)(gg[3] * scale * nw0.w);
    o8[4] = (__bf16)(gg[4] * scale * nw1.x);
    o8[5] = (__bf16)(gg[5] * scale * nw1.y);
    o8[6] = (__bf16)(gg[6] * scale * nw1.z);
    o8[7] = (__bf16)(gg[7] * scale * nw1.w);
    *(bf16x8*)(g + (size_t)m * DINNER + e0) = o8;
}

// ================= launch =================
extern "C" void kernel_launch(void* const* d_in, const int* in_sizes, int n_in,
                              void* d_out, int out_size, void* d_ws, size_t ws_size,
                              hipStream_t stream) {
    const float* x       = (const float*)d_in[0];
    const float* W_in    = (const float*)d_in[1];
    const float* conv_w  = (const float*)d_in[2];
    const float* conv_b  = (const float*)d_in[3];
    const float* dt_bias = (const float*)d_in[4];
    const float* A_log   = (const float*)d_in[5];
    const float* Dp      = (const float*)d_in[6];
    const float* norm_w  = (const float*)d_in[7];
    const float* W_out   = (const float*)d_in[8];
    float* out = (float*)d_out;

    if (ws_size < WS_NEED) {
        k_sentinel<<<1, 1, 0, stream>>>(out);
        return;
    }

    char* ws = (char*)d_ws;
    bf16* z     = (bf16*)(ws + OFF_Z);
    bf16* gb    = (bf16*)(ws + OFF_Z);    // g aliases z
    bf16* xbc   = (bf16*)(ws + OFF_XBC);
    bf16* st    = (bf16*)(ws + OFF_XBC);  // states alias xbc
    float* dtb  = (float*)(ws + OFF_DT);
    bf16* xs    = (bf16*)(ws + OFF_XS);
    bf16* yb    = (bf16*)(ws + OFF_XS);   // y aliases xs
    bf16* xb    = (bf16*)(ws + OFF_XS);   // bf16 x, dead before k_conv writes xs
    bf16* Bm    = (bf16*)(ws + OFF_B);
    bf16* Wbin  = (bf16*)(ws + OFF_B);    // bf16 W_in (padded), dead before k_conv writes Bm
    bf16* Cm    = (bf16*)(ws + OFF_C);
    bf16* G     = (bf16*)(ws + OFF_G);
    bf16* Wbout = (bf16*)(ws + OFF_G);    // bf16 W_out, cast after k_ssd consumed G
    float* asum = (float*)(ws + OFF_ASUM);

    k_cast_x<<<(MTOT * DMODEL / 4 + 255) / 256, 256, 0, stream>>>(x, xb, MTOT * DMODEL / 4);
    k_cast_win<<<(NPAD * DMODEL / 4 + 255) / 256, 256, 0, stream>>>(W_in, Wbin);
    k_gemm_in<<<dim3(NPAD / 128, MTOT / 128), 512, 0, stream>>>(xb, Wbin, dt_bias, z, xbc, dtb);
    k_conv<<<MTOT / CTOK, 320, 0, stream>>>(xbc, conv_w, conv_b, xs, Bm, Cm);
    k_gmat<<<dim3(2, 2, BSZ * NCHUNK), 64, 0, stream>>>(Cm, Bm, G);
    k_ssd<<<dim3(NHEADS, NCHUNK, BSZ), 256, 0, stream>>>(xs, Bm, dtb, A_log, Dp, G, yb, st, asum);
    k_cast_x<<<(DMODEL * DINNER / 4 + 255) / 256, 256, 0, stream>>>(W_out, Wbout, DMODEL * DINNER / 4);
    k_scan<<<dim3(NHEADS, BSZ, 16), 256, 0, stream>>>(st, asum);
    k_yoff<<<dim3(NHEADS, NCHUNK, BSZ), 256, 0, stream>>>(Cm, dtb, A_log, st, yb);
    k_norm<<<MTOT / 2, 256, 0, stream>>>(yb, z, norm_w, gb);
    k_gemm_out<<<dim3(DMODEL / 128, MTOT / 128), 512, 0, stream>>>(gb, Wbout, x, out);
}